// Round 1
// 17181.825 us; speedup vs baseline: 1.1461x; 1.1461x over previous
//
#include <hip/hip_runtime.h>

// GRU: T=2048, B=64, IN=H=256, L=3, 3H=768.
// v2 strategy (latency-bound fix):
//   gru_layer was 97% of time at ~7500 cyc/step vs ~2000 busy -> stall-bound on
//   the two full vmcnt(0) barrier drains per step (gx DMA from L3/HBM + stores).
//   Changes:
//   - gx written by gemm in per-thread FRAGMENT layout -> gru gate reads are 4
//     lane-linear ds_read_b128 (conflict-free), DMA'd 2 steps ahead into a
//     3-buffer LDS rotation.
//   - raw s_barrier + counted s_waitcnt vmcnt(12) (never 0 in-loop).
//   - ONE barrier/step: h_bf double-buffered (WAR barrier removed).
//   - h_old kept in registers (static (row,col) ownership) -> h_f LDS deleted.
//   - v_cvt_pk_bf16_f32 packed h/out writes, enabled by K-permuting Whh/Wih
//     storage (dot products are K-permutation invariant).
//   - s_setprio(1) around MFMA cluster.

typedef float  float4_  __attribute__((ext_vector_type(4)));
typedef short  short8_  __attribute__((ext_vector_type(8)));
typedef unsigned short ushort4_ __attribute__((ext_vector_type(4)));

#define DEVFN static __device__ __forceinline__

constexpr int T_ = 2048;
constexpr int B_ = 64;
constexpr int H_ = 256;
constexpr int G_ = 768;

DEVFN unsigned short f2bf(float f) {
  unsigned u = __float_as_uint(f);
  u += 0x7fffu + ((u >> 16) & 1u);   // round-to-nearest-even
  return (unsigned short)(u >> 16);
}
DEVFN float bf2f(unsigned short s) { return __uint_as_float(((unsigned)s) << 16); }
DEVFN unsigned cvt_pk_bf16(float lo, float hi) {   // lo -> D.lo, hi -> D.hi (RNE)
  unsigned r;
  asm("v_cvt_pk_bf16_f32 %0, %1, %2" : "=v"(r) : "v"(lo), "v"(hi));
  return r;
}
DEVFN float rcp_(float x)  { return __builtin_amdgcn_rcpf(x); }
DEVFN float exp2_(float x) { return __builtin_amdgcn_exp2f(x); }
DEVFN float sigmoid_(float x) { return rcp_(1.f + exp2_(-1.4426950408889634f * x)); }
DEVFN float tanh_(float x)    { return 1.f - 2.f * rcp_(1.f + exp2_(2.8853900817779268f * x)); }

DEVFN void load_lds16(const void* g, void* l) {
  __builtin_amdgcn_global_load_lds(
      (__attribute__((address_space(1))) void*)g,
      (__attribute__((address_space(3))) void*)l, 16, 0, 0);
}

// K-permutation: storage col sc -> original h col. Puts the (c=0,c=1) pair of
// each nl adjacent so gru writes h_bf as one packed b32 per row-pair.
// sc = w*32 + nl*2 + c  <->  orig = w*32 + c*16 + nl
DEVFN int korig(int sc) { return (sc & ~31) | ((sc & 1) << 4) | ((sc >> 1) & 15); }

// ---------------------------------------------------------------- convert ----
__global__ void convert_kernel(const float* __restrict__ x,
                               const float* __restrict__ wih,
                               const float* __restrict__ whh,
                               const float* __restrict__ bih,
                               const float* __restrict__ bhh,
                               unsigned short* __restrict__ xb,
                               unsigned short* __restrict__ wihb,
                               unsigned short* __restrict__ whhb,
                               float* __restrict__ biasf,
                               float* __restrict__ bhhn) {
  const long i0 = (long)blockIdx.x * blockDim.x + threadIdx.x;
  const long stride = (long)gridDim.x * blockDim.x;
  for (long i = i0; i < (long)T_ * B_ * H_; i += stride) xb[i] = f2bf(x[i]);
  for (long i = i0; i < 3L * G_ * H_; i += stride) {
    int row = (int)(i >> 8);
    int sc = (int)(i & 255);
    int ko = korig(sc);
    whhb[i] = f2bf(whh[(size_t)row * 256 + ko]);              // always K-permuted
    wihb[i] = f2bf(wih[(size_t)row * 256 + (row >= G_ ? ko : sc)]);  // l>=1 permuted
  }
  for (long i = i0; i < 3L * G_; i += stride) {
    int g = (int)(i % G_);
    biasf[i] = bih[i] + (g < 512 ? bhh[i] : 0.f);  // b_hh_n stays separate
  }
  for (long i = i0; i < 3L * H_; i += stride) {
    int l = (int)(i >> 8), j = (int)(i & 255);
    bhhn[i] = bhh[l * G_ + 512 + j];
  }
}

// ---------------------------------------------------------------- gemm_gx ----
// Computes gx = A @ W^T + bias, stores in gru fragment layout:
//   rzbuf chunk (16B) at [(t*4+wg)*1024 + c*512 + w*64 + q*16 + nl]:
//     [xr r=0..3 | xz r=0..3] bf16 for rows wg*16+q*4+r, col w*32+c*16+nl
//   nbuf  chunk (16B) same index: [xn r=0..3] f32
// gemm lane (q,nl) holds exactly acc[i][j][0..3] = 4 consecutive rows of one
// col -> one 8B (rz) or 16B (n) store per acc tile.
__global__ __launch_bounds__(256) void gemm_gx(const unsigned short* __restrict__ A,
                                               const unsigned short* __restrict__ W,
                                               const float* __restrict__ bias,
                                               unsigned short* __restrict__ rzbuf,
                                               float* __restrict__ nbuf) {
  __shared__ alignas(16) unsigned short As[128 * 32];
  __shared__ alignas(16) unsigned short Bs[128 * 32];
  const int tid = threadIdx.x;
  const int bn = blockIdx.x;
  const size_t bm = blockIdx.y;
  const int wave = tid >> 6, lane = tid & 63;
  const int q = lane >> 4, nl = lane & 15;
  const int wr = (wave >> 1) * 64, wc = (wave & 1) * 64;
  const unsigned short* Ab = A + bm * 128 * 256;
  const unsigned short* Wb = W + (size_t)bn * 128 * 256;

  float4_ acc[4][4];
  float4_ z4 = {0.f, 0.f, 0.f, 0.f};
#pragma unroll
  for (int i = 0; i < 4; ++i)
#pragma unroll
    for (int j = 0; j < 4; ++j) acc[i][j] = z4;

  for (int kt = 0; kt < 8; ++kt) {
    const int k0 = kt * 32;
#pragma unroll
    for (int cc = 0; cc < 2; ++cc) {
      int ch = tid + 256 * cc;  // 512 16B-chunks per tile
      load_lds16(Ab + (size_t)(ch >> 2) * 256 + k0 + (ch & 3) * 8, &As[ch * 8]);
      load_lds16(Wb + (size_t)(ch >> 2) * 256 + k0 + (ch & 3) * 8, &Bs[ch * 8]);
    }
    __syncthreads();  // drains global_load_lds (vmcnt) before use
    short8_ af[4], bf[4];
#pragma unroll
    for (int i = 0; i < 4; ++i) {
      af[i] = *(const short8_*)&As[(wr + i * 16 + nl) * 32 + q * 8];
      bf[i] = *(const short8_*)&Bs[(wc + i * 16 + nl) * 32 + q * 8];
    }
#pragma unroll
    for (int i = 0; i < 4; ++i)
#pragma unroll
      for (int j = 0; j < 4; ++j)
        acc[i][j] = __builtin_amdgcn_mfma_f32_16x16x32_bf16(af[i], bf[j], acc[i][j], 0, 0, 0);
    __syncthreads();
  }

  float bv[4];
#pragma unroll
  for (int j = 0; j < 4; ++j) bv[j] = bias[bn * 128 + wc + j * 16 + nl];

  if (bn < 4) {  // r,z columns -> bf16 fragments
    const int g2 = bn >> 1;  // 0 = r gate, 1 = z gate
#pragma unroll
    for (int i = 0; i < 4; ++i) {
      const int grow0 = (int)(bm * 128) + wr + i * 16 + q * 4;  // row of r=0
      const int t = grow0 >> 6, b = grow0 & 63;
      const size_t tb = ((size_t)(t * 4 + (b >> 4))) * 1024;
      const int qr = (b >> 2) & 3;
#pragma unroll
      for (int j = 0; j < 4; ++j) {
        const int hc = (bn * 128 + wc + j * 16 + nl) & 255;
        const int ch = ((hc >> 4) & 1) * 512 + (hc >> 5) * 64 + qr * 16 + (hc & 15);
        ushort4_ v;
#pragma unroll
        for (int r = 0; r < 4; ++r) v[r] = f2bf(acc[i][j][r] + bv[j]);
        *(ushort4_*)&rzbuf[(tb + ch) * 8 + g2 * 4] = v;
      }
    }
  } else {  // n columns -> f32 fragments (keep xn exact; tanh passes error at slope 1)
#pragma unroll
    for (int i = 0; i < 4; ++i) {
      const int grow0 = (int)(bm * 128) + wr + i * 16 + q * 4;
      const int t = grow0 >> 6, b = grow0 & 63;
      const size_t tb = ((size_t)(t * 4 + (b >> 4))) * 1024;
      const int qr = (b >> 2) & 3;
#pragma unroll
      for (int j = 0; j < 4; ++j) {
        const int hc = (bn * 128 + wc + j * 16 + nl) & 255;
        const int ch = ((hc >> 4) & 1) * 512 + (hc >> 5) * 64 + qr * 16 + (hc & 15);
        float4_ v;
#pragma unroll
        for (int r = 0; r < 4; ++r) v[r] = acc[i][j][r] + bv[j];
        *(float4_*)&nbuf[(tb + ch) * 4] = v;
      }
    }
  }
}

// --------------------------------------------------------------- gru_layer ---
// 4 WGs x 512 threads. WG b owns batch rows [16b,16b+16). Wave w owns h-cols
// [32w,32w+32): 6 acc tiles, Whh fragments resident in VGPRs (K-permuted order
// matching h_bf storage). ONE raw barrier per step; gx prefetched 2 steps ahead
// into a 3-buffer rotation with counted vmcnt (never drained to 0 in-loop).
DEVFN void pf_step(const unsigned short* rz_src, const float* n_src,
                   unsigned short* srz_dst, float* sn_dst, int tid) {
  load_lds16(rz_src + (size_t)tid * 8,         srz_dst + (size_t)tid * 8);
  load_lds16(rz_src + (size_t)(512 + tid) * 8, srz_dst + (size_t)(512 + tid) * 8);
  load_lds16(n_src + (size_t)tid * 4,          sn_dst + (size_t)tid * 4);
  load_lds16(n_src + (size_t)(512 + tid) * 4,  sn_dst + (size_t)(512 + tid) * 4);
}

__global__ __launch_bounds__(512, 2) void gru_layer(
    const unsigned short* __restrict__ rzbuf,  // fragment layout, bf16
    const float* __restrict__ nbuf,            // fragment layout, f32
    const unsigned short* __restrict__ whh,    // [768][256] bf16, K-permuted
    const float* __restrict__ bhhn,            // [256]
    const float* __restrict__ h0,              // [64][256] f32
    unsigned int* __restrict__ outb,           // [T*64][128] u32 (bf16 pairs, permuted cols) or null
    float* __restrict__ outf,                  // [T*64][256] f32 (final out) or null
    float* __restrict__ hT) {                  // [64][256] f32
  // h_bf: double-buffered, K-permuted cols; row stride 272 -> 4-way-max b128 reads.
  __shared__ alignas(16) unsigned short h_bf[2][16][272];
  __shared__ alignas(16) unsigned short srz[3][8192];  // 3 x 16KB rz fragments
  __shared__ alignas(16) float sn[3][4096];            // 3 x 16KB n fragments

  const int tid = threadIdx.x;
  const int wgid = blockIdx.x;
  const int rb = wgid * 16;
  const int w = tid >> 6, lane = tid & 63;
  const int q = lane >> 4, nl = lane & 15;
  const int cb = w * 32;

  // Whh fragments -> registers (storage K-order == h_bf storage order).
  short8_ wf[6][8];
#pragma unroll
  for (int c = 0; c < 2; ++c)
#pragma unroll
    for (int g = 0; g < 3; ++g) {
      const unsigned short* wrow = whh + (size_t)(g * 256 + cb + c * 16 + nl) * 256;
#pragma unroll
      for (int kt = 0; kt < 8; ++kt)
        wf[c * 3 + g][kt] = *(const short8_*)(wrow + kt * 32 + q * 8);
    }
  const float bn_[2] = { bhhn[cb + nl], bhhn[cb + 16 + nl] };

  // h0 -> registers (thread statically owns rows q*4+r, cols cb+{nl, 16+nl})
  float hold[2][4];
#pragma unroll
  for (int r = 0; r < 4; ++r) {
    hold[0][r] = h0[(rb + q * 4 + r) * 256 + cb + nl];
    hold[1][r] = h0[(rb + q * 4 + r) * 256 + cb + 16 + nl];
  }
#pragma unroll
  for (int r = 0; r < 4; ++r)
    *(unsigned*)&h_bf[0][q * 4 + r][cb + nl * 2] = cvt_pk_bf16(hold[0][r], hold[1][r]);

  // prefetch gx(t=0) -> buf0, gx(t=1) -> buf1
  pf_step(rzbuf + (size_t)(0 * 4 + wgid) * 1024 * 8, nbuf + (size_t)(0 * 4 + wgid) * 1024 * 4,
          &srz[0][0], &sn[0][0], tid);
  pf_step(rzbuf + (size_t)(1 * 4 + wgid) * 1024 * 8, nbuf + (size_t)(1 * 4 + wgid) * 1024 * 4,
          &srz[1][0], &sn[1][0], tid);
  // pf(0) complete (pf(1)'s 4 loads may remain in flight); h_bf[0] writes visible.
  asm volatile("s_waitcnt vmcnt(4) lgkmcnt(0)" ::: "memory");
  __builtin_amdgcn_s_barrier();
  asm volatile("" ::: "memory");

  int b3r = 0;  // buffer holding gx(t)
  for (int t = 0; t < T_; ++t) {
    // ---- issue prefetch gx(t+2) at top of step (max latency cover)
    {
      int tt = t + 2; if (tt > T_ - 1) tt = T_ - 1;       // harmless reload at tail
      int b3w = b3r + 2; if (b3w >= 3) b3w -= 3;
      const size_t base = ((size_t)tt * 4 + wgid) * 1024;
      pf_step(rzbuf + base * 8, nbuf + base * 4, &srz[b3w][0], &sn[b3w][0], tid);
    }
    asm volatile("" ::: "memory");  // pin pf-before-stores order (vmcnt accounting)

    // ---- MFMA: gh = h . Whh^T from h_bf[t&1]
    float4_ acc[6];
    float4_ z4 = {0.f, 0.f, 0.f, 0.f};
#pragma unroll
    for (int u = 0; u < 6; ++u) acc[u] = z4;
    __builtin_amdgcn_s_setprio(1);
#pragma unroll
    for (int kt = 0; kt < 8; ++kt) {
      const short8_ af = *(const short8_*)&h_bf[t & 1][nl][kt * 32 + q * 8];
#pragma unroll
      for (int u = 0; u < 6; ++u)
        acc[u] = __builtin_amdgcn_mfma_f32_16x16x32_bf16(af, wf[u][kt], acc[u], 0, 0, 0);
    }
    __builtin_amdgcn_s_setprio(0);

    // ---- gates: per-thread fragment reads (lane-linear b128, conflict-free)
    const short8_ rzA = *(const short8_*)&srz[b3r][(size_t)tid * 8];         // c=0: xr0..3,xz0..3
    const short8_ rzB = *(const short8_*)&srz[b3r][(size_t)(512 + tid) * 8]; // c=1
    const float4_ xnA = *(const float4_*)&sn[b3r][(size_t)tid * 4];
    const float4_ xnB = *(const float4_*)&sn[b3r][(size_t)(512 + tid) * 4];
    const size_t ob = ((size_t)t * 64 + rb) * 256;
#pragma unroll
    for (int r = 0; r < 4; ++r) {
      float rr0 = sigmoid_(bf2f((unsigned short)rzA[r]) + acc[0][r]);
      float zz0 = sigmoid_(bf2f((unsigned short)rzA[4 + r]) + acc[1][r]);
      float nn0 = tanh_(xnA[r] + rr0 * (acc[2][r] + bn_[0]));
      float hv0 = nn0 + zz0 * (hold[0][r] - nn0);
      float rr1 = sigmoid_(bf2f((unsigned short)rzB[r]) + acc[3][r]);
      float zz1 = sigmoid_(bf2f((unsigned short)rzB[4 + r]) + acc[4][r]);
      float nn1 = tanh_(xnB[r] + rr1 * (acc[5][r] + bn_[1]));
      float hv1 = nn1 + zz1 * (hold[1][r] - nn1);
      hold[0][r] = hv0;
      hold[1][r] = hv1;
      const unsigned pk = cvt_pk_bf16(hv0, hv1);
      *(unsigned*)&h_bf[(t + 1) & 1][q * 4 + r][cb + nl * 2] = pk;
      if (outb) outb[(ob >> 1) + (size_t)(q * 4 + r) * 128 + (cb >> 1) + nl] = pk;
    }
    if (outf) {
#pragma unroll
      for (int r = 0; r < 4; ++r) {
        outf[ob + (size_t)(q * 4 + r) * 256 + cb + nl] = hold[0][r];
        outf[ob + (size_t)(q * 4 + r) * 256 + cb + 16 + nl] = hold[1][r];
      }
    }

    // ---- counted-vmcnt barrier: guarantees pf(t+1) landed; stores + pf(t+2)
    // stay in flight. FIFO after pf(t+1): st(t-1)[<=8] + pf(t+2)[4] + st(t)[<=8];
    // with S=4 (outb) counts are exact, with S=8 (outf) slightly conservative.
    asm volatile("" ::: "memory");
    if (t == 0) {
      asm volatile("s_waitcnt vmcnt(8) lgkmcnt(0)" ::: "memory");
    } else {
      asm volatile("s_waitcnt vmcnt(12) lgkmcnt(0)" ::: "memory");
    }
    __builtin_amdgcn_s_barrier();
    asm volatile("" ::: "memory");  // no memory op crosses above the barrier
    b3r = (b3r == 2) ? 0 : b3r + 1;
  }

  // final hidden state from registers
#pragma unroll
  for (int r = 0; r < 4; ++r) {
    hT[(rb + q * 4 + r) * 256 + cb + nl] = hold[0][r];
    hT[(rb + q * 4 + r) * 256 + cb + 16 + nl] = hold[1][r];
  }
}

// ------------------------------------------------------------------ launch ---
extern "C" void kernel_launch(void* const* d_in, const int* in_sizes, int n_in,
                              void* d_out, int out_size, void* d_ws, size_t ws_size,
                              hipStream_t stream) {
  (void)in_sizes; (void)n_in; (void)out_size; (void)ws_size;
  const float* x   = (const float*)d_in[0];
  const float* h0  = (const float*)d_in[1];
  const float* wih = (const float*)d_in[2];
  const float* whh = (const float*)d_in[3];
  const float* bih = (const float*)d_in[4];
  const float* bhh = (const float*)d_in[5];
  float* out = (float*)d_out;
  char* ws = (char*)d_ws;

  // workspace layout (total ~386 MiB)
  unsigned short* rzbuf = (unsigned short*)(ws + 0);          // 134,217,728
  float*          nbuf  = (float*)(ws + 134217728);           // 134,217,728
  unsigned short* buf0  = (unsigned short*)(ws + 268435456);  //  67,108,864
  unsigned short* buf1  = (unsigned short*)(ws + 335544320);  //  67,108,864
  unsigned short* wihb  = (unsigned short*)(ws + 402653184);  //   1,179,648
  unsigned short* whhb  = (unsigned short*)(ws + 403832832);  //   1,179,648
  float*         biasf  = (float*)(ws + 405012480);           //       9,216
  float*          bhhn  = (float*)(ws + 405021696);           //       3,072

  convert_kernel<<<2048, 256, 0, stream>>>(x, wih, whh, bih, bhh,
                                           buf0, wihb, whhb, biasf, bhhn);

  for (int l = 0; l < 3; ++l) {
    const unsigned short* inb = (l & 1) ? buf1 : buf0;
    unsigned short* outbuf    = (l & 1) ? buf0 : buf1;
    gemm_gx<<<dim3(6, 1024), 256, 0, stream>>>(inb, wihb + (size_t)l * G_ * H_,
                                               biasf + l * G_, rzbuf, nbuf);
    gru_layer<<<4, 512, 0, stream>>>(
        rzbuf, nbuf, whhb + (size_t)l * G_ * H_, bhhn + l * H_,
        h0 + (size_t)l * B_ * H_,
        (l < 2) ? (unsigned int*)outbuf : (unsigned int*)nullptr,
        (l == 2) ? out : (float*)nullptr,
        out + (size_t)T_ * B_ * H_ + (size_t)l * B_ * H_);
  }
}

// Round 2
// 7882.578 us; speedup vs baseline: 2.4981x; 2.1797x over previous
//
#include <hip/hip_runtime.h>

// GRU: T=2048, B=64, IN=H=256, L=3, 3H=768.
// v3: LAYER PIPELINING. The 3 recurrences ran serially on 4 CUs (16.8/17.2ms).
// Layer l at step t only needs layer l-1's step-t output -> run all layers
// concurrently in ONE persistent kernel (20 active WGs), connected per-step by
// device-scope release/acquire flags:
//   A-stage (per layer, 4 WGs): v2's recurrence; layers 0/1 publish h(t) as
//     packed bf16 pairs to an 8-slot ring. Layer 0 reads precomputed gx.
//   B-stage (layers 0,1; 4 WGs): consumes h(t), computes gx_{l+1}(t) =
//     h @ Wih^T + bias (Wih register-resident, 48 MFMA/wave) and writes the
//     fragment layout A's DMA prefetch expects into an 8-slot L2-resident ring.
// Flags are monotonic step counters; consumers cache the last-seen value so
// steady-state polls are register-compares (producers run ahead by ring depth).

typedef float  float4_  __attribute__((ext_vector_type(4)));
typedef short  short8_  __attribute__((ext_vector_type(8)));
typedef unsigned short ushort4_ __attribute__((ext_vector_type(4)));
typedef unsigned int   uint4_   __attribute__((ext_vector_type(4)));

#define DEVFN static __device__ __forceinline__

constexpr int T_ = 2048;
constexpr int B_ = 64;
constexpr int H_ = 256;
constexpr int G_ = 768;

// ring geometry (8 slots each)
constexpr int HRING_L  = 8 * 4 * 2048;    // u32 per layer-ring (h pairs)
constexpr int RZRING_L = 8 * 4 * 1024 * 8;  // ushort per layer-ring
constexpr int NRING_L  = 8 * 4 * 1024 * 4;  // float per layer-ring

DEVFN unsigned short f2bf(float f) {
  unsigned u = __float_as_uint(f);
  u += 0x7fffu + ((u >> 16) & 1u);   // round-to-nearest-even
  return (unsigned short)(u >> 16);
}
DEVFN float bf2f(unsigned short s) { return __uint_as_float(((unsigned)s) << 16); }
DEVFN unsigned cvt_pk_bf16(float lo, float hi) {   // lo -> D.lo, hi -> D.hi (RNE)
  unsigned r;
  asm("v_cvt_pk_bf16_f32 %0, %1, %2" : "=v"(r) : "v"(lo), "v"(hi));
  return r;
}
DEVFN float rcp_(float x)  { return __builtin_amdgcn_rcpf(x); }
DEVFN float exp2_(float x) { return __builtin_amdgcn_exp2f(x); }
DEVFN float sigmoid_(float x) { return rcp_(1.f + exp2_(-1.4426950408889634f * x)); }
DEVFN float tanh_(float x)    { return 1.f - 2.f * rcp_(1.f + exp2_(2.8853900817779268f * x)); }

DEVFN void load_lds16(const void* g, void* l) {
  __builtin_amdgcn_global_load_lds(
      (__attribute__((address_space(1))) void*)g,
      (__attribute__((address_space(3))) void*)l, 16, 0, 0);
}

DEVFN void acq_fence() { __builtin_amdgcn_fence(__ATOMIC_ACQUIRE, "agent"); }
DEVFN void rel_fence() { __builtin_amdgcn_fence(__ATOMIC_RELEASE, "agent"); }

DEVFN int pollGE(const int* f, int target) {
  int v = __hip_atomic_load(f, __ATOMIC_RELAXED, __HIP_MEMORY_SCOPE_AGENT);
  while (v < target) {
    __builtin_amdgcn_s_sleep(2);
    v = __hip_atomic_load(f, __ATOMIC_RELAXED, __HIP_MEMORY_SCOPE_AGENT);
  }
  return v;
}

// K-permutation: storage col sc -> original h col (pairs adjacent for cvt_pk).
DEVFN int korig(int sc) { return (sc & ~31) | ((sc & 1) << 4) | ((sc >> 1) & 15); }

// ---------------------------------------------------------------- convert ----
__global__ void convert_kernel(const float* __restrict__ x,
                               const float* __restrict__ wih,
                               const float* __restrict__ whh,
                               const float* __restrict__ bih,
                               const float* __restrict__ bhh,
                               unsigned short* __restrict__ xb,
                               unsigned short* __restrict__ wihb,
                               unsigned short* __restrict__ whhb,
                               float* __restrict__ biasf,
                               float* __restrict__ bhhn,
                               int* __restrict__ flags) {
  const long i0 = (long)blockIdx.x * blockDim.x + threadIdx.x;
  const long stride = (long)gridDim.x * blockDim.x;
  for (long i = i0; i < 32; i += stride) flags[i] = 0;   // pipeline flags
  for (long i = i0; i < (long)T_ * B_ * H_; i += stride) xb[i] = f2bf(x[i]);
  for (long i = i0; i < 3L * G_ * H_; i += stride) {
    int row = (int)(i >> 8);
    int sc = (int)(i & 255);
    int ko = korig(sc);
    whhb[i] = f2bf(whh[(size_t)row * 256 + ko]);              // always K-permuted
    wihb[i] = f2bf(wih[(size_t)row * 256 + (row >= G_ ? ko : sc)]);  // l>=1 permuted
  }
  for (long i = i0; i < 3L * G_; i += stride) {
    int g = (int)(i % G_);
    biasf[i] = bih[i] + (g < 512 ? bhh[i] : 0.f);  // b_hh_n stays separate
  }
  for (long i = i0; i < 3L * H_; i += stride) {
    int l = (int)(i >> 8), j = (int)(i & 255);
    bhhn[i] = bhh[l * G_ + 512 + j];
  }
}

// ---------------------------------------------------------------- gemm_gx ----
// Layer-0 only: gx = x_bf16 @ Wih^T + bias, stored in gru fragment layout.
__global__ __launch_bounds__(256) void gemm_gx(const unsigned short* __restrict__ A,
                                               const unsigned short* __restrict__ W,
                                               const float* __restrict__ bias,
                                               unsigned short* __restrict__ rzbuf,
                                               float* __restrict__ nbuf) {
  __shared__ alignas(16) unsigned short As[128 * 32];
  __shared__ alignas(16) unsigned short Bs[128 * 32];
  const int tid = threadIdx.x;
  const int bn = blockIdx.x;
  const size_t bm = blockIdx.y;
  const int wave = tid >> 6, lane = tid & 63;
  const int q = lane >> 4, nl = lane & 15;
  const int wr = (wave >> 1) * 64, wc = (wave & 1) * 64;
  const unsigned short* Ab = A + bm * 128 * 256;
  const unsigned short* Wb = W + (size_t)bn * 128 * 256;

  float4_ acc[4][4];
  float4_ z4 = {0.f, 0.f, 0.f, 0.f};
#pragma unroll
  for (int i = 0; i < 4; ++i)
#pragma unroll
    for (int j = 0; j < 4; ++j) acc[i][j] = z4;

  for (int kt = 0; kt < 8; ++kt) {
    const int k0 = kt * 32;
#pragma unroll
    for (int cc = 0; cc < 2; ++cc) {
      int ch = tid + 256 * cc;
      load_lds16(Ab + (size_t)(ch >> 2) * 256 + k0 + (ch & 3) * 8, &As[ch * 8]);
      load_lds16(Wb + (size_t)(ch >> 2) * 256 + k0 + (ch & 3) * 8, &Bs[ch * 8]);
    }
    __syncthreads();
    short8_ af[4], bf[4];
#pragma unroll
    for (int i = 0; i < 4; ++i) {
      af[i] = *(const short8_*)&As[(wr + i * 16 + nl) * 32 + q * 8];
      bf[i] = *(const short8_*)&Bs[(wc + i * 16 + nl) * 32 + q * 8];
    }
#pragma unroll
    for (int i = 0; i < 4; ++i)
#pragma unroll
      for (int j = 0; j < 4; ++j)
        acc[i][j] = __builtin_amdgcn_mfma_f32_16x16x32_bf16(af[i], bf[j], acc[i][j], 0, 0, 0);
    __syncthreads();
  }

  float bv[4];
#pragma unroll
  for (int j = 0; j < 4; ++j) bv[j] = bias[bn * 128 + wc + j * 16 + nl];

  if (bn < 4) {  // r,z -> bf16 fragments
#pragma unroll
    for (int i = 0; i < 4; ++i) {
      const int grow0 = (int)(bm * 128) + wr + i * 16 + q * 4;
      const int t = grow0 >> 6, b = grow0 & 63;
      const size_t tb = ((size_t)(t * 4 + (b >> 4))) * 1024;
      const int qr = (b >> 2) & 3;
      const int g2 = bn >> 1;
#pragma unroll
      for (int j = 0; j < 4; ++j) {
        const int hc = (bn * 128 + wc + j * 16 + nl) & 255;
        const int ch = ((hc >> 4) & 1) * 512 + (hc >> 5) * 64 + qr * 16 + (hc & 15);
        ushort4_ v;
#pragma unroll
        for (int r = 0; r < 4; ++r) v[r] = f2bf(acc[i][j][r] + bv[j]);
        *(ushort4_*)&rzbuf[(tb + ch) * 8 + g2 * 4] = v;
      }
    }
  } else {  // n -> f32 fragments
#pragma unroll
    for (int i = 0; i < 4; ++i) {
      const int grow0 = (int)(bm * 128) + wr + i * 16 + q * 4;
      const int t = grow0 >> 6, b = grow0 & 63;
      const size_t tb = ((size_t)(t * 4 + (b >> 4))) * 1024;
      const int qr = (b >> 2) & 3;
#pragma unroll
      for (int j = 0; j < 4; ++j) {
        const int hc = (bn * 128 + wc + j * 16 + nl) & 255;
        const int ch = ((hc >> 4) & 1) * 512 + (hc >> 5) * 64 + qr * 16 + (hc & 15);
        float4_ v;
#pragma unroll
        for (int r = 0; r < 4; ++r) v[r] = acc[i][j][r] + bv[j];
        *(float4_*)&nbuf[(tb + ch) * 4] = v;
      }
    }
  }
}

// ------------------------------------------------------------------- roles ---
DEVFN void pfA(const unsigned short* rz_src, const float* n_src,
               unsigned short* srz_dst, float* sn_dst, int tid) {
  load_lds16(rz_src + (size_t)tid * 8,         srz_dst + (size_t)tid * 8);
  load_lds16(rz_src + (size_t)(512 + tid) * 8, srz_dst + (size_t)(512 + tid) * 8);
  load_lds16(n_src + (size_t)tid * 4,          sn_dst + (size_t)tid * 4);
  load_lds16(n_src + (size_t)(512 + tid) * 4,  sn_dst + (size_t)(512 + tid) * 4);
}

// A-stage: the recurrence. L=0 reads big gx buffers; L>=1 reads gx ring.
// L<=1 publishes h(t) pairs + flag; L==2 writes final out.
template <int L>
DEVFN void gruA(char* smem,
                const unsigned short* rzsrc, const float* nsrc,
                const unsigned short* whh, const float* bhhn_l,
                const float* h0_l, float* outf, float* hTl,
                unsigned* hring_l, int* fBprod, int* fBself, int* fAself, int b) {
  auto h_bf = (unsigned short(*)[16][272])(smem);                 // [2][16][272]
  auto srz  = (unsigned short(*)[8192])(smem + 17408);            // [2][8192]
  auto sn   = (float(*)[4096])(smem + 17408 + 32768);             // [2][4096]

  const int tid = threadIdx.x;
  const int w = tid >> 6, lane = tid & 63;
  const int q = lane >> 4, nl = lane & 15;
  const int cb = w * 32;

  // Whh fragments -> registers (K-permuted storage order).
  short8_ wf[6][8];
#pragma unroll
  for (int c = 0; c < 2; ++c)
#pragma unroll
    for (int g = 0; g < 3; ++g) {
      const unsigned short* wrow = whh + (size_t)(g * 256 + cb + c * 16 + nl) * 256;
#pragma unroll
      for (int kt = 0; kt < 8; ++kt)
        wf[c * 3 + g][kt] = *(const short8_*)(wrow + kt * 32 + q * 8);
    }
  const float bn_[2] = { bhhn_l[cb + nl], bhhn_l[cb + 16 + nl] };

  float hold[2][4];
#pragma unroll
  for (int r = 0; r < 4; ++r) {
    hold[0][r] = h0_l[(b * 16 + q * 4 + r) * 256 + cb + nl];
    hold[1][r] = h0_l[(b * 16 + q * 4 + r) * 256 + cb + 16 + nl];
  }
#pragma unroll
  for (int r = 0; r < 4; ++r)
    *(unsigned*)&h_bf[0][q * 4 + r][cb + nl * 2] = cvt_pk_bf16(hold[0][r], hold[1][r]);

  int seenB = 0, seenBs = 0;
  // prologue: gx(0) -> buf 0
  if (L > 0) { seenB = pollGE(fBprod, 1); acq_fence(); }
  {
    const size_t base = (L == 0 ? (size_t)b : (size_t)b) * 1024;  // slot 0
    pfA(rzsrc + base * 8, nsrc + base * 4, &srz[0][0], &sn[0][0], tid);
  }
  __syncthreads();   // drains pf(0) + h_bf[0] ds writes

  for (int t = 0; t < T_; ++t) {
    const int tt = (t + 1 < T_) ? t + 1 : T_ - 1;
    if (L > 0) {
      if (seenB < tt + 1) { seenB = pollGE(fBprod, tt + 1); acq_fence(); }
    }
    if (L <= 1) {
      if (t >= 8 && seenBs < t - 7) seenBs = pollGE(fBself, t - 7);  // h-ring reuse
    }
    {  // prefetch gx(t+1) -> buf (t+1)&1 (overlaps MFMA+gates)
      const size_t base = (L == 0 ? ((size_t)tt * 4 + b) : ((size_t)(tt & 7) * 4 + b)) * 1024;
      pfA(rzsrc + base * 8, nsrc + base * 4, &srz[(t + 1) & 1][0], &sn[(t + 1) & 1][0], tid);
    }
    asm volatile("" ::: "memory");

    // ---- MFMA: gh = h . Whh^T from h_bf[t&1]
    float4_ acc[6];
    float4_ z4 = {0.f, 0.f, 0.f, 0.f};
#pragma unroll
    for (int u = 0; u < 6; ++u) acc[u] = z4;
    __builtin_amdgcn_s_setprio(1);
#pragma unroll
    for (int kt = 0; kt < 8; ++kt) {
      const short8_ af = *(const short8_*)&h_bf[t & 1][nl][kt * 32 + q * 8];
#pragma unroll
      for (int u = 0; u < 6; ++u)
        acc[u] = __builtin_amdgcn_mfma_f32_16x16x32_bf16(af, wf[u][kt], acc[u], 0, 0, 0);
    }
    __builtin_amdgcn_s_setprio(0);

    // ---- gates (fragment reads: lane-linear b128, conflict-free)
    const short8_ rzA = *(const short8_*)&srz[t & 1][(size_t)tid * 8];
    const short8_ rzB = *(const short8_*)&srz[t & 1][(size_t)(512 + tid) * 8];
    const float4_ xnA = *(const float4_*)&sn[t & 1][(size_t)tid * 4];
    const float4_ xnB = *(const float4_*)&sn[t & 1][(size_t)(512 + tid) * 4];
#pragma unroll
    for (int r = 0; r < 4; ++r) {
      float rr0 = sigmoid_(bf2f((unsigned short)rzA[r]) + acc[0][r]);
      float zz0 = sigmoid_(bf2f((unsigned short)rzA[4 + r]) + acc[1][r]);
      float nn0 = tanh_(xnA[r] + rr0 * (acc[2][r] + bn_[0]));
      float hv0 = nn0 + zz0 * (hold[0][r] - nn0);
      float rr1 = sigmoid_(bf2f((unsigned short)rzB[r]) + acc[3][r]);
      float zz1 = sigmoid_(bf2f((unsigned short)rzB[4 + r]) + acc[4][r]);
      float nn1 = tanh_(xnB[r] + rr1 * (acc[5][r] + bn_[1]));
      float hv1 = nn1 + zz1 * (hold[1][r] - nn1);
      hold[0][r] = hv0;
      hold[1][r] = hv1;
      const unsigned pk = cvt_pk_bf16(hv0, hv1);
      *(unsigned*)&h_bf[(t + 1) & 1][q * 4 + r][cb + nl * 2] = pk;
      if (L <= 1)
        hring_l[((size_t)(t & 7) * 4 + b) * 2048 + (size_t)(q * 4 + r) * 128 + (cb >> 1) + nl] = pk;
    }
    if (L == 2) {
      const size_t ob = ((size_t)t * 64 + b * 16) * 256;
#pragma unroll
      for (int r = 0; r < 4; ++r) {
        outf[ob + (size_t)(q * 4 + r) * 256 + cb + nl] = hold[0][r];
        outf[ob + (size_t)(q * 4 + r) * 256 + cb + 16 + nl] = hold[1][r];
      }
    }

    if (L <= 1) {
      __syncthreads();   // vmcnt(0)+lgkmcnt(0)+barrier: pf(t+1) landed, h stores in L2
      if (tid == 0) {
        rel_fence();     // L2 writeback -> h(t) visible device-wide
        __hip_atomic_store(fAself, t + 1, __ATOMIC_RELAXED, __HIP_MEMORY_SCOPE_AGENT);
      }
    } else {
      // counted: exactly 8 out-stores are newer than pf(t+1) -> vmcnt(8) proves
      // pf(t+1) complete; out stores stay in flight.
      asm volatile("s_waitcnt vmcnt(8) lgkmcnt(0)" ::: "memory");
      __builtin_amdgcn_s_barrier();
      asm volatile("" ::: "memory");
      if (tid == 0)      // gx-ring reuse flag (reads drained; anti-dep only)
        __hip_atomic_store(fAself, t + 1, __ATOMIC_RELAXED, __HIP_MEMORY_SCOPE_AGENT);
    }
  }

#pragma unroll
  for (int r = 0; r < 4; ++r) {
    hTl[(b * 16 + q * 4 + r) * 256 + cb + nl] = hold[0][r];
    hTl[(b * 16 + q * 4 + r) * 256 + cb + 16 + nl] = hold[1][r];
  }
}

// B-stage: gx_{L+1}(t) = h_L(t) @ Wih^T + bias -> fragment ring.
template <int LB>
DEVFN void gruB(const unsigned* hring_l, const unsigned short* wih, const float* bias,
                unsigned short* rzdst, float* ndst,
                int* fAh, int* fAnext, int* fBself, int b) {
  const int tid = threadIdx.x;
  const int w = tid >> 6, lane = tid & 63;
  const int q = lane >> 4, nl = lane & 15;
  const int cb = w * 32;

  short8_ wf[6][8];
#pragma unroll
  for (int c = 0; c < 2; ++c)
#pragma unroll
    for (int g = 0; g < 3; ++g) {
      const unsigned short* wrow = wih + (size_t)(g * 256 + cb + c * 16 + nl) * 256;
#pragma unroll
      for (int kt = 0; kt < 8; ++kt)
        wf[c * 3 + g][kt] = *(const short8_*)(wrow + kt * 32 + q * 8);
    }
  float bv[6];
#pragma unroll
  for (int c = 0; c < 2; ++c)
#pragma unroll
    for (int g = 0; g < 3; ++g) bv[c * 3 + g] = bias[g * 256 + cb + c * 16 + nl];

  int seenA = 0, seenAn = 0;
  for (int t = 0; t < T_; ++t) {
    if (seenA < t + 1) { seenA = pollGE(fAh, t + 1); acq_fence(); }
    if (t >= 8 && seenAn < t - 7) seenAn = pollGE(fAnext, t - 7);  // gx-ring reuse

    const unsigned* hrow = hring_l + ((size_t)(t & 7) * 4 + b) * 2048 + (size_t)nl * 128;
    float4_ acc[6];
    float4_ z4 = {0.f, 0.f, 0.f, 0.f};
#pragma unroll
    for (int u = 0; u < 6; ++u) acc[u] = z4;
#pragma unroll
    for (int h = 0; h < 2; ++h) {
      short8_ af4[4];
#pragma unroll
      for (int k = 0; k < 4; ++k)
        af4[k] = *(const short8_*)(hrow + (h * 4 + k) * 16 + q * 4);
#pragma unroll
      for (int k = 0; k < 4; ++k)
#pragma unroll
        for (int u = 0; u < 6; ++u)
          acc[u] = __builtin_amdgcn_mfma_f32_16x16x32_bf16(af4[k], wf[u][h * 4 + k], acc[u], 0, 0, 0);
    }

    const size_t base = ((size_t)(t & 7) * 4 + b) * 1024;
#pragma unroll
    for (int c = 0; c < 2; ++c) {
      const int ch = c * 512 + w * 64 + q * 16 + nl;
      uint4_ rv;
      rv[0] = cvt_pk_bf16(acc[c * 3 + 0][0] + bv[c * 3 + 0], acc[c * 3 + 0][1] + bv[c * 3 + 0]);
      rv[1] = cvt_pk_bf16(acc[c * 3 + 0][2] + bv[c * 3 + 0], acc[c * 3 + 0][3] + bv[c * 3 + 0]);
      rv[2] = cvt_pk_bf16(acc[c * 3 + 1][0] + bv[c * 3 + 1], acc[c * 3 + 1][1] + bv[c * 3 + 1]);
      rv[3] = cvt_pk_bf16(acc[c * 3 + 1][2] + bv[c * 3 + 1], acc[c * 3 + 1][3] + bv[c * 3 + 1]);
      *(uint4_*)(rzdst + (base + ch) * 8) = rv;
      float4_ nv;
#pragma unroll
      for (int r = 0; r < 4; ++r) nv[r] = acc[c * 3 + 2][r] + bv[c * 3 + 2];
      *(float4_*)(ndst + (base + ch) * 4) = nv;
    }

    __syncthreads();   // per-wave vmcnt(0): all stores in L2
    if (tid == 0) {
      rel_fence();
      __hip_atomic_store(fBself, t + 1, __ATOMIC_RELAXED, __HIP_MEMORY_SCOPE_AGENT);
    }
  }
}

// -------------------------------------------------------------- pipeline -----
__global__ __launch_bounds__(512, 2) void gru_pipeline(
    const unsigned short* __restrict__ gxrz0, const float* __restrict__ gxn0,
    unsigned short* __restrict__ rzring, float* __restrict__ nring,
    unsigned* __restrict__ hring,
    const unsigned short* __restrict__ whhb, const unsigned short* __restrict__ wihb,
    const float* __restrict__ biasf, const float* __restrict__ bhhn,
    const float* __restrict__ h0, float* __restrict__ out, float* __restrict__ hT,
    int* __restrict__ flags) {
  __shared__ alignas(16) char smem[17408 + 32768 + 32768];
  const int bid = (int)blockIdx.x;
  const int role = bid >> 3, b = bid & 7;
  if (b >= 4) return;   // XCD-chain placement: chain b sits on XCD b (perf only)
  int* fA = flags;        // [3][4]
  int* fB = flags + 12;   // [2][4]

  if (role == 0) {
    gruA<0>(smem, gxrz0, gxn0, whhb, bhhn, h0, nullptr, hT,
            hring, nullptr, &fB[b], &fA[b], b);
  } else if (role == 1) {
    gruB<0>(hring, wihb + (size_t)1 * G_ * H_, biasf + G_,
            rzring, nring, &fA[b], &fA[4 + b], &fB[b], b);
  } else if (role == 2) {
    gruA<1>(smem, rzring, nring, whhb + (size_t)1 * G_ * H_, bhhn + H_,
            h0 + B_ * H_, nullptr, hT + B_ * H_,
            hring + HRING_L, &fB[b], &fB[4 + b], &fA[4 + b], b);
  } else if (role == 3) {
    gruB<1>(hring + HRING_L, wihb + (size_t)2 * G_ * H_, biasf + 2 * G_,
            rzring + RZRING_L, nring + NRING_L, &fA[4 + b], &fA[8 + b], &fB[4 + b], b);
  } else {
    gruA<2>(smem, rzring + RZRING_L, nring + NRING_L, whhb + (size_t)2 * G_ * H_,
            bhhn + 2 * H_, h0 + 2 * B_ * H_, out, hT + 2 * B_ * H_,
            nullptr, &fB[4 + b], nullptr, &fA[8 + b], b);
  }
}

// ------------------------------------------------------------------ launch ---
extern "C" void kernel_launch(void* const* d_in, const int* in_sizes, int n_in,
                              void* d_out, int out_size, void* d_ws, size_t ws_size,
                              hipStream_t stream) {
  (void)in_sizes; (void)n_in; (void)out_size; (void)ws_size;
  const float* x   = (const float*)d_in[0];
  const float* h0  = (const float*)d_in[1];
  const float* wih = (const float*)d_in[2];
  const float* whh = (const float*)d_in[3];
  const float* bih = (const float*)d_in[4];
  const float* bhh = (const float*)d_in[5];
  float* out = (float*)d_out;
  char* ws = (char*)d_ws;

  // workspace layout (within previous 405 MiB footprint)
  unsigned short* gxrz0 = (unsigned short*)(ws + 0);           // 134,217,728
  float*          gxn0  = (float*)(ws + 134217728);            // 134,217,728
  unsigned short* buf0  = (unsigned short*)(ws + 268435456);   //  67,108,864 (x bf16)
  unsigned*       hring = (unsigned*)(ws + 335544320);         //     524,288
  unsigned short* rzring= (unsigned short*)(ws + 336068608);   //   1,048,576
  float*          nring = (float*)(ws + 337117184);            //   1,048,576
  int*            flags = (int*)(ws + 338165760);              //         128
  unsigned short* wihb  = (unsigned short*)(ws + 402653184);   //   1,179,648
  unsigned short* whhb  = (unsigned short*)(ws + 403832832);   //   1,179,648
  float*         biasf  = (float*)(ws + 405012480);            //       9,216
  float*          bhhn  = (float*)(ws + 405021696);            //       3,072

  convert_kernel<<<2048, 256, 0, stream>>>(x, wih, whh, bih, bhh,
                                           buf0, wihb, whhb, biasf, bhhn, flags);
  gemm_gx<<<dim3(6, 1024), 256, 0, stream>>>(buf0, wihb, biasf, gxrz0, gxn0);
  gru_pipeline<<<40, 512, 0, stream>>>(gxrz0, gxn0, rzring, nring, hring,
                                       whhb, wihb, biasf, bhhn, h0,
                                       out, out + (size_t)T_ * B_ * H_, flags);
}

// Round 3
// 7122.993 us; speedup vs baseline: 2.7645x; 1.1066x over previous
//
#include <hip/hip_runtime.h>

// GRU: T=2048, B=64, IN=H=256, L=3, 3H=768.
// v4: v3 (layer pipelining) + two fixes:
//  1. __launch_bounds__(512,1): v3's (512,2) capped VGPRs at 128, silently
//     spilling the 192-VGPR weight fragments -> ~393KB/WG/step of L2 weight
//     reloads on the MFMA operand path. Only 20 WGs run; occupancy>1 is useless.
//  2. Counted-vmcnt raw barriers everywhere (pf 2 ahead, 3-buffer LDS, vmcnt
//     never 0 in-loop) and amortized flags: publish every 2 steps at TOP of
//     step (drained ops are ~1 step old -> cheap wave0 fence), lag-2 semantics,
//     ring depth 16 so reuse polls amortize.

typedef float  float4_  __attribute__((ext_vector_type(4)));
typedef short  short8_  __attribute__((ext_vector_type(8)));
typedef unsigned short ushort4_ __attribute__((ext_vector_type(4)));
typedef unsigned int   uint4_   __attribute__((ext_vector_type(4)));

#define DEVFN static __device__ __forceinline__

constexpr int T_ = 2048;
constexpr int B_ = 64;
constexpr int H_ = 256;
constexpr int G_ = 768;

// ring geometry (16 slots each)
constexpr int HRING_L  = 16 * 4 * 2048;      // u32 per layer-ring (h pairs)
constexpr int RZRING_L = 16 * 4 * 1024 * 8;  // ushort per layer-ring
constexpr int NRING_L  = 16 * 4 * 1024 * 4;  // float per layer-ring

DEVFN unsigned short f2bf(float f) {
  unsigned u = __float_as_uint(f);
  u += 0x7fffu + ((u >> 16) & 1u);   // round-to-nearest-even
  return (unsigned short)(u >> 16);
}
DEVFN float bf2f(unsigned short s) { return __uint_as_float(((unsigned)s) << 16); }
DEVFN unsigned cvt_pk_bf16(float lo, float hi) {
  unsigned r;
  asm("v_cvt_pk_bf16_f32 %0, %1, %2" : "=v"(r) : "v"(lo), "v"(hi));
  return r;
}
DEVFN float rcp_(float x)  { return __builtin_amdgcn_rcpf(x); }
DEVFN float exp2_(float x) { return __builtin_amdgcn_exp2f(x); }
DEVFN float sigmoid_(float x) { return rcp_(1.f + exp2_(-1.4426950408889634f * x)); }
DEVFN float tanh_(float x)    { return 1.f - 2.f * rcp_(1.f + exp2_(2.8853900817779268f * x)); }

DEVFN void load_lds16(const void* g, void* l) {
  __builtin_amdgcn_global_load_lds(
      (__attribute__((address_space(1))) void*)g,
      (__attribute__((address_space(3))) void*)l, 16, 0, 0);
}

DEVFN void acq_fence() { __builtin_amdgcn_fence(__ATOMIC_ACQUIRE, "agent"); }
DEVFN void rel_fence() { __builtin_amdgcn_fence(__ATOMIC_RELEASE, "agent"); }

DEVFN int pollGE(const int* f, int target) {
  int v = __hip_atomic_load(f, __ATOMIC_RELAXED, __HIP_MEMORY_SCOPE_AGENT);
  while (v < target) {
    __builtin_amdgcn_s_sleep(2);
    v = __hip_atomic_load(f, __ATOMIC_RELAXED, __HIP_MEMORY_SCOPE_AGENT);
  }
  return v;
}

// K-permutation: storage col sc -> original h col (pairs adjacent for cvt_pk).
DEVFN int korig(int sc) { return (sc & ~31) | ((sc & 1) << 4) | ((sc >> 1) & 15); }

// ---------------------------------------------------------------- convert ----
__global__ void convert_kernel(const float* __restrict__ x,
                               const float* __restrict__ wih,
                               const float* __restrict__ whh,
                               const float* __restrict__ bih,
                               const float* __restrict__ bhh,
                               unsigned short* __restrict__ xb,
                               unsigned short* __restrict__ wihb,
                               unsigned short* __restrict__ whhb,
                               float* __restrict__ biasf,
                               float* __restrict__ bhhn,
                               int* __restrict__ flags) {
  const long i0 = (long)blockIdx.x * blockDim.x + threadIdx.x;
  const long stride = (long)gridDim.x * blockDim.x;
  for (long i = i0; i < 32; i += stride) flags[i] = 0;
  for (long i = i0; i < (long)T_ * B_ * H_; i += stride) xb[i] = f2bf(x[i]);
  for (long i = i0; i < 3L * G_ * H_; i += stride) {
    int row = (int)(i >> 8);
    int sc = (int)(i & 255);
    int ko = korig(sc);
    whhb[i] = f2bf(whh[(size_t)row * 256 + ko]);
    wihb[i] = f2bf(wih[(size_t)row * 256 + (row >= G_ ? ko : sc)]);
  }
  for (long i = i0; i < 3L * G_; i += stride) {
    int g = (int)(i % G_);
    biasf[i] = bih[i] + (g < 512 ? bhh[i] : 0.f);
  }
  for (long i = i0; i < 3L * H_; i += stride) {
    int l = (int)(i >> 8), j = (int)(i & 255);
    bhhn[i] = bhh[l * G_ + 512 + j];
  }
}

// ---------------------------------------------------------------- gemm_gx ----
// Layer-0 only: gx = x_bf16 @ Wih^T + bias, stored in gru fragment layout.
__global__ __launch_bounds__(256) void gemm_gx(const unsigned short* __restrict__ A,
                                               const unsigned short* __restrict__ W,
                                               const float* __restrict__ bias,
                                               unsigned short* __restrict__ rzbuf,
                                               float* __restrict__ nbuf) {
  __shared__ alignas(16) unsigned short As[128 * 32];
  __shared__ alignas(16) unsigned short Bs[128 * 32];
  const int tid = threadIdx.x;
  const int bn = blockIdx.x;
  const size_t bm = blockIdx.y;
  const int wave = tid >> 6, lane = tid & 63;
  const int q = lane >> 4, nl = lane & 15;
  const int wr = (wave >> 1) * 64, wc = (wave & 1) * 64;
  const unsigned short* Ab = A + bm * 128 * 256;
  const unsigned short* Wb = W + (size_t)bn * 128 * 256;

  float4_ acc[4][4];
  float4_ z4 = {0.f, 0.f, 0.f, 0.f};
#pragma unroll
  for (int i = 0; i < 4; ++i)
#pragma unroll
    for (int j = 0; j < 4; ++j) acc[i][j] = z4;

  for (int kt = 0; kt < 8; ++kt) {
    const int k0 = kt * 32;
#pragma unroll
    for (int cc = 0; cc < 2; ++cc) {
      int ch = tid + 256 * cc;
      load_lds16(Ab + (size_t)(ch >> 2) * 256 + k0 + (ch & 3) * 8, &As[ch * 8]);
      load_lds16(Wb + (size_t)(ch >> 2) * 256 + k0 + (ch & 3) * 8, &Bs[ch * 8]);
    }
    __syncthreads();
    short8_ af[4], bf[4];
#pragma unroll
    for (int i = 0; i < 4; ++i) {
      af[i] = *(const short8_*)&As[(wr + i * 16 + nl) * 32 + q * 8];
      bf[i] = *(const short8_*)&Bs[(wc + i * 16 + nl) * 32 + q * 8];
    }
#pragma unroll
    for (int i = 0; i < 4; ++i)
#pragma unroll
      for (int j = 0; j < 4; ++j)
        acc[i][j] = __builtin_amdgcn_mfma_f32_16x16x32_bf16(af[i], bf[j], acc[i][j], 0, 0, 0);
    __syncthreads();
  }

  float bv[4];
#pragma unroll
  for (int j = 0; j < 4; ++j) bv[j] = bias[bn * 128 + wc + j * 16 + nl];

  if (bn < 4) {  // r,z -> bf16 fragments
#pragma unroll
    for (int i = 0; i < 4; ++i) {
      const int grow0 = (int)(bm * 128) + wr + i * 16 + q * 4;
      const int t = grow0 >> 6, b = grow0 & 63;
      const size_t tb = ((size_t)(t * 4 + (b >> 4))) * 1024;
      const int qr = (b >> 2) & 3;
      const int g2 = bn >> 1;
#pragma unroll
      for (int j = 0; j < 4; ++j) {
        const int hc = (bn * 128 + wc + j * 16 + nl) & 255;
        const int ch = ((hc >> 4) & 1) * 512 + (hc >> 5) * 64 + qr * 16 + (hc & 15);
        ushort4_ v;
#pragma unroll
        for (int r = 0; r < 4; ++r) v[r] = f2bf(acc[i][j][r] + bv[j]);
        *(ushort4_*)&rzbuf[(tb + ch) * 8 + g2 * 4] = v;
      }
    }
  } else {  // n -> f32 fragments
#pragma unroll
    for (int i = 0; i < 4; ++i) {
      const int grow0 = (int)(bm * 128) + wr + i * 16 + q * 4;
      const int t = grow0 >> 6, b = grow0 & 63;
      const size_t tb = ((size_t)(t * 4 + (b >> 4))) * 1024;
      const int qr = (b >> 2) & 3;
#pragma unroll
      for (int j = 0; j < 4; ++j) {
        const int hc = (bn * 128 + wc + j * 16 + nl) & 255;
        const int ch = ((hc >> 4) & 1) * 512 + (hc >> 5) * 64 + qr * 16 + (hc & 15);
        float4_ v;
#pragma unroll
        for (int r = 0; r < 4; ++r) v[r] = acc[i][j][r] + bv[j];
        *(float4_*)&nbuf[(tb + ch) * 4] = v;
      }
    }
  }
}

// ------------------------------------------------------------------- roles ---
DEVFN void pfA(const unsigned short* rz_src, const float* n_src,
               unsigned short* srz_dst, float* sn_dst, int tid) {
  load_lds16(rz_src + (size_t)tid * 8,         srz_dst + (size_t)tid * 8);
  load_lds16(rz_src + (size_t)(512 + tid) * 8, srz_dst + (size_t)(512 + tid) * 8);
  load_lds16(n_src + (size_t)tid * 4,          sn_dst + (size_t)tid * 4);
  load_lds16(n_src + (size_t)(512 + tid) * 4,  sn_dst + (size_t)(512 + tid) * 4);
}

// A-stage: the recurrence. Per-step vm ops: pf(4) + stores(4 for L<=1, 8 for
// L==2). End-of-step waits vmcnt(8)/vmcnt(12): drains pf(t+1) + stores(t-1),
// leaves pf(t+2)+stores(t) in flight. Flags published every 2 steps at TOP of
// step t (even): value t-1 => h <= t-2 visible / gx-reads <= t done.
template <int L>
DEVFN void gruA(char* smem,
                const unsigned short* rzsrc, const float* nsrc,
                const unsigned short* whh, const float* bhhn_l,
                const float* h0_l, float* outf, float* hTl,
                unsigned* hring_l, int* fBprod, int* fBself, int* fAself, int b) {
  auto h_bf = (unsigned short(*)[16][272])(smem);              // [2][16][272]
  auto srz  = (unsigned short(*)[8192])(smem + 17408);         // [3][8192]
  auto sn   = (float(*)[4096])(smem + 17408 + 49152);          // [3][4096]

  const int tid = threadIdx.x;
  const int w = tid >> 6, lane = tid & 63;
  const int q = lane >> 4, nl = lane & 15;
  const int cb = w * 32;

  // Whh fragments -> registers (192 VGPR; needs launch_bounds(512,1)).
  short8_ wf[6][8];
#pragma unroll
  for (int c = 0; c < 2; ++c)
#pragma unroll
    for (int g = 0; g < 3; ++g) {
      const unsigned short* wrow = whh + (size_t)(g * 256 + cb + c * 16 + nl) * 256;
#pragma unroll
      for (int kt = 0; kt < 8; ++kt)
        wf[c * 3 + g][kt] = *(const short8_*)(wrow + kt * 32 + q * 8);
    }
  const float bn_[2] = { bhhn_l[cb + nl], bhhn_l[cb + 16 + nl] };

  float hold[2][4];
#pragma unroll
  for (int r = 0; r < 4; ++r) {
    hold[0][r] = h0_l[(b * 16 + q * 4 + r) * 256 + cb + nl];
    hold[1][r] = h0_l[(b * 16 + q * 4 + r) * 256 + cb + 16 + nl];
  }
#pragma unroll
  for (int r = 0; r < 4; ++r)
    *(unsigned*)&h_bf[0][q * 4 + r][cb + nl * 2] = cvt_pk_bf16(hold[0][r], hold[1][r]);

  int seenB = 0, seenBs = 0;
  if (L > 0) { seenB = pollGE(fBprod, 2); acq_fence(); }   // gx(0),gx(1) visible
  {
    const size_t b0 = (size_t)b * 1024;
    const size_t b1 = ((size_t)4 + b) * 1024;
    pfA(rzsrc + b0 * 8, nsrc + b0 * 4, &srz[0][0], &sn[0][0], tid);
    pfA(rzsrc + b1 * 8, nsrc + b1 * 4, &srz[1][0], &sn[1][0], tid);
  }
  asm volatile("s_waitcnt vmcnt(4) lgkmcnt(0)" ::: "memory");  // pf(0) done
  __builtin_amdgcn_s_barrier();
  asm volatile("" ::: "memory");

  int b3r = 0;  // LDS buffer holding gx(t)
  for (int t = 0; t < T_; ++t) {
    // ---- publish (every 2 steps, top-of-step: drained ops are ~1 step old)
    if (((t & 1) == 0) && t >= 2 && tid == 0) {
      if (L <= 1) rel_fence();       // h-ring data release (wbl2)
      __hip_atomic_store(fAself, t - 1, __ATOMIC_RELAXED, __HIP_MEMORY_SCOPE_AGENT);
    }
    const int tt = (t + 2 <= T_ - 1) ? t + 2 : T_ - 1;
    if (L > 0) {
      if (seenB < tt + 1) { seenB = pollGE(fBprod, tt + 1); acq_fence(); }
    }
    if (L <= 1) {
      if (t >= 16 && seenBs < t - 15) seenBs = pollGE(fBself, t - 15);  // h-ring reuse
    }
    {  // prefetch gx(t+2) -> LDS buffer (t+2)%3
      int b3w = b3r + 2; if (b3w >= 3) b3w -= 3;
      const size_t base = (L == 0 ? ((size_t)tt * 4 + b) : ((size_t)(tt & 15) * 4 + b)) * 1024;
      pfA(rzsrc + base * 8, nsrc + base * 4, &srz[b3w][0], &sn[b3w][0], tid);
    }
    asm volatile("" ::: "memory");   // pin pf-before-stores (vmcnt accounting)

    // ---- MFMA: gh = h . Whh^T from h_bf[t&1]
    float4_ acc[6];
    float4_ z4 = {0.f, 0.f, 0.f, 0.f};
#pragma unroll
    for (int u = 0; u < 6; ++u) acc[u] = z4;
    __builtin_amdgcn_s_setprio(1);
#pragma unroll
    for (int kt = 0; kt < 8; ++kt) {
      const short8_ af = *(const short8_*)&h_bf[t & 1][nl][kt * 32 + q * 8];
#pragma unroll
      for (int u = 0; u < 6; ++u)
        acc[u] = __builtin_amdgcn_mfma_f32_16x16x32_bf16(af, wf[u][kt], acc[u], 0, 0, 0);
    }
    __builtin_amdgcn_s_setprio(0);

    // ---- gates (lane-linear b128 fragment reads, conflict-free)
    const short8_ rzA = *(const short8_*)&srz[b3r][(size_t)tid * 8];
    const short8_ rzB = *(const short8_*)&srz[b3r][(size_t)(512 + tid) * 8];
    const float4_ xnA = *(const float4_*)&sn[b3r][(size_t)tid * 4];
    const float4_ xnB = *(const float4_*)&sn[b3r][(size_t)(512 + tid) * 4];
#pragma unroll
    for (int r = 0; r < 4; ++r) {
      float rr0 = sigmoid_(bf2f((unsigned short)rzA[r]) + acc[0][r]);
      float zz0 = sigmoid_(bf2f((unsigned short)rzA[4 + r]) + acc[1][r]);
      float nn0 = tanh_(xnA[r] + rr0 * (acc[2][r] + bn_[0]));
      float hv0 = nn0 + zz0 * (hold[0][r] - nn0);
      float rr1 = sigmoid_(bf2f((unsigned short)rzB[r]) + acc[3][r]);
      float zz1 = sigmoid_(bf2f((unsigned short)rzB[4 + r]) + acc[4][r]);
      float nn1 = tanh_(xnB[r] + rr1 * (acc[5][r] + bn_[1]));
      float hv1 = nn1 + zz1 * (hold[1][r] - nn1);
      hold[0][r] = hv0;
      hold[1][r] = hv1;
      const unsigned pk = cvt_pk_bf16(hv0, hv1);
      *(unsigned*)&h_bf[(t + 1) & 1][q * 4 + r][cb + nl * 2] = pk;
      if (L <= 1)
        hring_l[((size_t)(t & 15) * 4 + b) * 2048 + (size_t)(q * 4 + r) * 128 + (cb >> 1) + nl] = pk;
    }
    if (L == 2) {
      const size_t ob = ((size_t)t * 64 + b * 16) * 256;
#pragma unroll
      for (int r = 0; r < 4; ++r) {
        outf[ob + (size_t)(q * 4 + r) * 256 + cb + nl] = hold[0][r];
        outf[ob + (size_t)(q * 4 + r) * 256 + cb + 16 + nl] = hold[1][r];
      }
    }

    // ---- counted barrier: pf(t+1) + stores(t-1) drained; pf(t+2)+stores(t)
    // stay in flight. Never vmcnt(0) in-loop.
    asm volatile("" ::: "memory");
    if (L == 2) asm volatile("s_waitcnt vmcnt(12) lgkmcnt(0)" ::: "memory");
    else        asm volatile("s_waitcnt vmcnt(8) lgkmcnt(0)" ::: "memory");
    __builtin_amdgcn_s_barrier();
    asm volatile("" ::: "memory");
    b3r = (b3r == 2) ? 0 : b3r + 1;
  }

  // epilogue: final hidden state, then terminal flag
#pragma unroll
  for (int r = 0; r < 4; ++r) {
    hTl[(b * 16 + q * 4 + r) * 256 + cb + nl] = hold[0][r];
    hTl[(b * 16 + q * 4 + r) * 256 + cb + 16 + nl] = hold[1][r];
  }
  asm volatile("s_waitcnt vmcnt(0) lgkmcnt(0)" ::: "memory");
  __builtin_amdgcn_s_barrier();
  if (tid == 0 && fAself) {
    if (L <= 1) rel_fence();
    __hip_atomic_store(fAself, T_ + 2, __ATOMIC_RELAXED, __HIP_MEMORY_SCOPE_AGENT);
  }
}

// B-stage: gx_{L+1}(t) = h_L(t) @ Wih^T + bias -> fragment ring.
// Per-step vm ops: loads(8) + stores(4) = 12; end-of-step vmcnt(12) drains
// step t-1. Publish every 2 at top of step t: value t-1 => gx <= t-2 visible,
// h-reads <= t-2 done.
template <int LB>
DEVFN void gruB(const unsigned* hring_l, const unsigned short* wih, const float* bias,
                unsigned short* rzdst, float* ndst,
                int* fAh, int* fAnext, int* fBself, int b) {
  const int tid = threadIdx.x;
  const int w = tid >> 6, lane = tid & 63;
  const int q = lane >> 4, nl = lane & 15;
  const int cb = w * 32;

  short8_ wf[6][8];
#pragma unroll
  for (int c = 0; c < 2; ++c)
#pragma unroll
    for (int g = 0; g < 3; ++g) {
      const unsigned short* wrow = wih + (size_t)(g * 256 + cb + c * 16 + nl) * 256;
#pragma unroll
      for (int kt = 0; kt < 8; ++kt)
        wf[c * 3 + g][kt] = *(const short8_*)(wrow + kt * 32 + q * 8);
    }
  float bv[6];
#pragma unroll
  for (int c = 0; c < 2; ++c)
#pragma unroll
    for (int g = 0; g < 3; ++g) bv[c * 3 + g] = bias[g * 256 + cb + c * 16 + nl];

  int seenA = 0, seenAn = 0;
  for (int t = 0; t < T_; ++t) {
    if (((t & 1) == 0) && t >= 2 && tid == 0) {
      rel_fence();
      __hip_atomic_store(fBself, t - 1, __ATOMIC_RELAXED, __HIP_MEMORY_SCOPE_AGENT);
    }
    if (seenA < t + 1) { seenA = pollGE(fAh, t + 1); acq_fence(); }
    if (t >= 16 && seenAn < t - 15) seenAn = pollGE(fAnext, t - 15);  // gx-ring reuse

    const unsigned* hrow = hring_l + ((size_t)(t & 15) * 4 + b) * 2048 + (size_t)nl * 128;
    float4_ acc[6];
    float4_ z4 = {0.f, 0.f, 0.f, 0.f};
#pragma unroll
    for (int u = 0; u < 6; ++u) acc[u] = z4;
#pragma unroll
    for (int h = 0; h < 2; ++h) {
      short8_ af4[4];
#pragma unroll
      for (int k = 0; k < 4; ++k)
        af4[k] = *(const short8_*)(hrow + (h * 4 + k) * 16 + q * 4);
      __builtin_amdgcn_s_setprio(1);
#pragma unroll
      for (int k = 0; k < 4; ++k)
#pragma unroll
        for (int u = 0; u < 6; ++u)
          acc[u] = __builtin_amdgcn_mfma_f32_16x16x32_bf16(af4[k], wf[u][h * 4 + k], acc[u], 0, 0, 0);
      __builtin_amdgcn_s_setprio(0);
    }

    const size_t base = ((size_t)(t & 15) * 4 + b) * 1024;
#pragma unroll
    for (int c = 0; c < 2; ++c) {
      const int ch = c * 512 + w * 64 + q * 16 + nl;
      uint4_ rv;
      rv[0] = cvt_pk_bf16(acc[c * 3 + 0][0] + bv[c * 3 + 0], acc[c * 3 + 0][1] + bv[c * 3 + 0]);
      rv[1] = cvt_pk_bf16(acc[c * 3 + 0][2] + bv[c * 3 + 0], acc[c * 3 + 0][3] + bv[c * 3 + 0]);
      rv[2] = cvt_pk_bf16(acc[c * 3 + 1][0] + bv[c * 3 + 1], acc[c * 3 + 1][1] + bv[c * 3 + 1]);
      rv[3] = cvt_pk_bf16(acc[c * 3 + 1][2] + bv[c * 3 + 1], acc[c * 3 + 1][3] + bv[c * 3 + 1]);
      *(uint4_*)(rzdst + (base + ch) * 8) = rv;
      float4_ nv;
#pragma unroll
      for (int r = 0; r < 4; ++r) nv[r] = acc[c * 3 + 2][r] + bv[c * 3 + 2];
      *(float4_*)(ndst + (base + ch) * 4) = nv;
    }

    asm volatile("" ::: "memory");
    asm volatile("s_waitcnt vmcnt(12) lgkmcnt(0)" ::: "memory");
    __builtin_amdgcn_s_barrier();
    asm volatile("" ::: "memory");
  }

  asm volatile("s_waitcnt vmcnt(0) lgkmcnt(0)" ::: "memory");
  __builtin_amdgcn_s_barrier();
  if (tid == 0) {
    rel_fence();
    __hip_atomic_store(fBself, T_ + 2, __ATOMIC_RELAXED, __HIP_MEMORY_SCOPE_AGENT);
  }
}

// -------------------------------------------------------------- pipeline -----
__global__ __launch_bounds__(512, 1) void gru_pipeline(
    const unsigned short* __restrict__ gxrz0, const float* __restrict__ gxn0,
    unsigned short* __restrict__ rzring, float* __restrict__ nring,
    unsigned* __restrict__ hring,
    const unsigned short* __restrict__ whhb, const unsigned short* __restrict__ wihb,
    const float* __restrict__ biasf, const float* __restrict__ bhhn,
    const float* __restrict__ h0, float* __restrict__ out, float* __restrict__ hT,
    int* __restrict__ flags) {
  __shared__ alignas(16) char smem[17408 + 49152 + 49152];
  const int bid = (int)blockIdx.x;
  const int role = bid >> 3, b = bid & 7;
  if (b >= 4) return;   // XCD-chain placement heuristic: chain b on XCD b
  int* fA = flags;        // [3][4]: A-stage progress flags
  int* fB = flags + 12;   // [2][4]: B-stage progress flags

  if (role == 0) {
    gruA<0>(smem, gxrz0, gxn0, whhb, bhhn, h0, nullptr, hT,
            hring, nullptr, &fB[b], &fA[b], b);
  } else if (role == 1) {
    gruB<0>(hring, wihb + (size_t)1 * G_ * H_, biasf + G_,
            rzring, nring, &fA[b], &fA[4 + b], &fB[b], b);
  } else if (role == 2) {
    gruA<1>(smem, rzring, nring, whhb + (size_t)1 * G_ * H_, bhhn + H_,
            h0 + B_ * H_, nullptr, hT + B_ * H_,
            hring + HRING_L, &fB[b], &fB[4 + b], &fA[4 + b], b);
  } else if (role == 3) {
    gruB<1>(hring + HRING_L, wihb + (size_t)2 * G_ * H_, biasf + 2 * G_,
            rzring + RZRING_L, nring + NRING_L, &fA[4 + b], &fA[8 + b], &fB[4 + b], b);
  } else {
    gruA<2>(smem, rzring + RZRING_L, nring + NRING_L, whhb + (size_t)2 * G_ * H_,
            bhhn + 2 * H_, h0 + 2 * B_ * H_, out, hT + 2 * B_ * H_,
            nullptr, &fB[4 + b], nullptr, &fA[8 + b], b);
  }
}

// ------------------------------------------------------------------ launch ---
extern "C" void kernel_launch(void* const* d_in, const int* in_sizes, int n_in,
                              void* d_out, int out_size, void* d_ws, size_t ws_size,
                              hipStream_t stream) {
  (void)in_sizes; (void)n_in; (void)out_size; (void)ws_size;
  const float* x   = (const float*)d_in[0];
  const float* h0  = (const float*)d_in[1];
  const float* wih = (const float*)d_in[2];
  const float* whh = (const float*)d_in[3];
  const float* bih = (const float*)d_in[4];
  const float* bhh = (const float*)d_in[5];
  float* out = (float*)d_out;
  char* ws = (char*)d_ws;

  // workspace layout (within previous 405 MiB footprint)
  unsigned short* gxrz0 = (unsigned short*)(ws + 0);           // 134,217,728
  float*          gxn0  = (float*)(ws + 134217728);            // 134,217,728
  unsigned short* buf0  = (unsigned short*)(ws + 268435456);   //  67,108,864 (x bf16)
  unsigned*       hring = (unsigned*)(ws + 335544320);         //   1,048,576
  unsigned short* rzring= (unsigned short*)(ws + 336592896);   //   2,097,152
  float*          nring = (float*)(ws + 338690048);            //   2,097,152
  int*            flags = (int*)(ws + 340787200);              //         128
  unsigned short* wihb  = (unsigned short*)(ws + 402653184);   //   1,179,648
  unsigned short* whhb  = (unsigned short*)(ws + 403832832);   //   1,179,648
  float*         biasf  = (float*)(ws + 405012480);            //       9,216
  float*          bhhn  = (float*)(ws + 405021696);            //       3,072

  convert_kernel<<<2048, 256, 0, stream>>>(x, wih, whh, bih, bhh,
                                           buf0, wihb, whhb, biasf, bhhn, flags);
  gemm_gx<<<dim3(6, 1024), 256, 0, stream>>>(buf0, wihb, biasf, gxrz0, gxn0);
  gru_pipeline<<<40, 512, 0, stream>>>(gxrz0, gxn0, rzring, nring, hring,
                                       whhb, wihb, biasf, bhhn, h0,
                                       out, out + (size_t)T_ * B_ * H_, flags);
}

// Round 6
// 6821.335 us; speedup vs baseline: 2.8867x; 1.0442x over previous
//
#include <hip/hip_runtime.h>

// GRU: T=2048, B=64, IN=H=256, L=3, 3H=768.
// v7: layer-pipelined persistent kernel (v3/v4 architecture) with PROVEN
// coherence primitives (rel/acq agent fences, as in v4 which passed) at 1/4
// the cadence:
//  - publish = synchronized mini-phase every 4 steps: all waves vmcnt(0) +
//    barrier, then tid0 rel_fence (wbl2) + flag=t. Flag >= g+1 => data g
//    visible. Ring 16 slots; all reuse margins re-derived (slack >= 2).
//  - acq_fence only when a guarded poll actually executes (~every 4 steps).
//  - B-stages: no per-step barrier (no LDS; publish-block barrier bounds wave
//    drift), v4's 2-group register h loads (fits 256 VGPR, no spill).
//  - A-stages: v4-proven global_load_lds 2-ahead 3-buffer + counted vmcnt.
//  - A2's flag is reuse-only (anti-dependency) -> published without fence.

typedef float  float4_  __attribute__((ext_vector_type(4)));
typedef short  short8_  __attribute__((ext_vector_type(8)));
typedef unsigned short ushort4_ __attribute__((ext_vector_type(4)));
typedef unsigned int   uint4_   __attribute__((ext_vector_type(4)));

#define DEVFN static __device__ __forceinline__

constexpr int T_ = 2048;
constexpr int B_ = 64;
constexpr int H_ = 256;
constexpr int G_ = 768;

// ring geometry (16 slots each)
constexpr int HRING_L  = 16 * 4 * 2048;      // u32 per layer-ring (h pairs)
constexpr int RZRING_L = 16 * 4 * 1024 * 8;  // ushort per layer-ring
constexpr int NRING_L  = 16 * 4 * 1024 * 4;  // float per layer-ring

DEVFN unsigned short f2bf(float f) {
  unsigned u = __float_as_uint(f);
  u += 0x7fffu + ((u >> 16) & 1u);   // round-to-nearest-even
  return (unsigned short)(u >> 16);
}
DEVFN float bf2f(unsigned short s) { return __uint_as_float(((unsigned)s) << 16); }
DEVFN unsigned cvt_pk_bf16(float lo, float hi) {
  unsigned r;
  asm("v_cvt_pk_bf16_f32 %0, %1, %2" : "=v"(r) : "v"(lo), "v"(hi));
  return r;
}
DEVFN float rcp_(float x)  { return __builtin_amdgcn_rcpf(x); }
DEVFN float exp2_(float x) { return __builtin_amdgcn_exp2f(x); }
DEVFN float sigmoid_(float x) { return rcp_(1.f + exp2_(-1.4426950408889634f * x)); }
DEVFN float tanh_(float x)    { return 1.f - 2.f * rcp_(1.f + exp2_(2.8853900817779268f * x)); }

DEVFN void load_lds16(const void* g, void* l) {
  __builtin_amdgcn_global_load_lds(
      (__attribute__((address_space(1))) void*)g,
      (__attribute__((address_space(3))) void*)l, 16, 0, 0);
}

DEVFN void acq_fence() { __builtin_amdgcn_fence(__ATOMIC_ACQUIRE, "agent"); }
DEVFN void rel_fence() { __builtin_amdgcn_fence(__ATOMIC_RELEASE, "agent"); }

DEVFN int pollGE(const int* f, int target) {
  int v = __hip_atomic_load(f, __ATOMIC_RELAXED, __HIP_MEMORY_SCOPE_AGENT);
  while (v < target) {
    __builtin_amdgcn_s_sleep(2);
    v = __hip_atomic_load(f, __ATOMIC_RELAXED, __HIP_MEMORY_SCOPE_AGENT);
  }
  return v;
}
DEVFN void flag_pub(int* f, int v) {
  __hip_atomic_store(f, v, __ATOMIC_RELAXED, __HIP_MEMORY_SCOPE_AGENT);
}

// K-permutation: storage col sc -> original h col (pairs adjacent for cvt_pk).
DEVFN int korig(int sc) { return (sc & ~31) | ((sc & 1) << 4) | ((sc >> 1) & 15); }

// ---------------------------------------------------------------- convert ----
__global__ void convert_kernel(const float* __restrict__ x,
                               const float* __restrict__ wih,
                               const float* __restrict__ whh,
                               const float* __restrict__ bih,
                               const float* __restrict__ bhh,
                               unsigned short* __restrict__ xb,
                               unsigned short* __restrict__ wihb,
                               unsigned short* __restrict__ whhb,
                               float* __restrict__ biasf,
                               float* __restrict__ bhhn,
                               int* __restrict__ flags) {
  const long i0 = (long)blockIdx.x * blockDim.x + threadIdx.x;
  const long stride = (long)gridDim.x * blockDim.x;
  for (long i = i0; i < 32; i += stride) flags[i] = 0;
  for (long i = i0; i < (long)T_ * B_ * H_; i += stride) xb[i] = f2bf(x[i]);
  for (long i = i0; i < 3L * G_ * H_; i += stride) {
    int row = (int)(i >> 8);
    int sc = (int)(i & 255);
    int ko = korig(sc);
    whhb[i] = f2bf(whh[(size_t)row * 256 + ko]);
    wihb[i] = f2bf(wih[(size_t)row * 256 + (row >= G_ ? ko : sc)]);
  }
  for (long i = i0; i < 3L * G_; i += stride) {
    int g = (int)(i % G_);
    biasf[i] = bih[i] + (g < 512 ? bhh[i] : 0.f);
  }
  for (long i = i0; i < 3L * H_; i += stride) {
    int l = (int)(i >> 8), j = (int)(i & 255);
    bhhn[i] = bhh[l * G_ + 512 + j];
  }
}

// ---------------------------------------------------------------- gemm_gx ----
// Layer-0 only: gx = x_bf16 @ Wih^T + bias, stored in gru fragment layout.
__global__ __launch_bounds__(256) void gemm_gx(const unsigned short* __restrict__ A,
                                               const unsigned short* __restrict__ W,
                                               const float* __restrict__ bias,
                                               unsigned short* __restrict__ rzbuf,
                                               float* __restrict__ nbuf) {
  __shared__ alignas(16) unsigned short As[128 * 32];
  __shared__ alignas(16) unsigned short Bs[128 * 32];
  const int tid = threadIdx.x;
  const int bn = blockIdx.x;
  const size_t bm = blockIdx.y;
  const int wave = tid >> 6, lane = tid & 63;
  const int q = lane >> 4, nl = lane & 15;
  const int wr = (wave >> 1) * 64, wc = (wave & 1) * 64;
  const unsigned short* Ab = A + bm * 128 * 256;
  const unsigned short* Wb = W + (size_t)bn * 128 * 256;

  float4_ acc[4][4];
  float4_ z4 = {0.f, 0.f, 0.f, 0.f};
#pragma unroll
  for (int i = 0; i < 4; ++i)
#pragma unroll
    for (int j = 0; j < 4; ++j) acc[i][j] = z4;

  for (int kt = 0; kt < 8; ++kt) {
    const int k0 = kt * 32;
#pragma unroll
    for (int cc = 0; cc < 2; ++cc) {
      int ch = tid + 256 * cc;
      load_lds16(Ab + (size_t)(ch >> 2) * 256 + k0 + (ch & 3) * 8, &As[ch * 8]);
      load_lds16(Wb + (size_t)(ch >> 2) * 256 + k0 + (ch & 3) * 8, &Bs[ch * 8]);
    }
    __syncthreads();
    short8_ af[4], bf[4];
#pragma unroll
    for (int i = 0; i < 4; ++i) {
      af[i] = *(const short8_*)&As[(wr + i * 16 + nl) * 32 + q * 8];
      bf[i] = *(const short8_*)&Bs[(wc + i * 16 + nl) * 32 + q * 8];
    }
#pragma unroll
    for (int i = 0; i < 4; ++i)
#pragma unroll
      for (int j = 0; j < 4; ++j)
        acc[i][j] = __builtin_amdgcn_mfma_f32_16x16x32_bf16(af[i], bf[j], acc[i][j], 0, 0, 0);
    __syncthreads();
  }

  float bv[4];
#pragma unroll
  for (int j = 0; j < 4; ++j) bv[j] = bias[bn * 128 + wc + j * 16 + nl];

  if (bn < 4) {  // r,z -> bf16 fragments
#pragma unroll
    for (int i = 0; i < 4; ++i) {
      const int grow0 = (int)(bm * 128) + wr + i * 16 + q * 4;
      const int t = grow0 >> 6, b = grow0 & 63;
      const size_t tb = ((size_t)(t * 4 + (b >> 4))) * 1024;
      const int qr = (b >> 2) & 3;
      const int g2 = bn >> 1;
#pragma unroll
      for (int j = 0; j < 4; ++j) {
        const int hc = (bn * 128 + wc + j * 16 + nl) & 255;
        const int ch = ((hc >> 4) & 1) * 512 + (hc >> 5) * 64 + qr * 16 + (hc & 15);
        ushort4_ v;
#pragma unroll
        for (int r = 0; r < 4; ++r) v[r] = f2bf(acc[i][j][r] + bv[j]);
        *(ushort4_*)&rzbuf[(tb + ch) * 8 + g2 * 4] = v;
      }
    }
  } else {  // n -> f32 fragments
#pragma unroll
    for (int i = 0; i < 4; ++i) {
      const int grow0 = (int)(bm * 128) + wr + i * 16 + q * 4;
      const int t = grow0 >> 6, b = grow0 & 63;
      const size_t tb = ((size_t)(t * 4 + (b >> 4))) * 1024;
      const int qr = (b >> 2) & 3;
#pragma unroll
      for (int j = 0; j < 4; ++j) {
        const int hc = (bn * 128 + wc + j * 16 + nl) & 255;
        const int ch = ((hc >> 4) & 1) * 512 + (hc >> 5) * 64 + qr * 16 + (hc & 15);
        float4_ v;
#pragma unroll
        for (int r = 0; r < 4; ++r) v[r] = acc[i][j][r] + bv[j];
        *(float4_*)&nbuf[(tb + ch) * 4] = v;
      }
    }
  }
}

// ------------------------------------------------------------------- roles ---
DEVFN void pfA(const unsigned short* rz_src, const float* n_src,
               unsigned short* srz_dst, float* sn_dst, int tid) {
  load_lds16(rz_src + (size_t)tid * 8,         srz_dst + (size_t)tid * 8);
  load_lds16(rz_src + (size_t)(512 + tid) * 8, srz_dst + (size_t)(512 + tid) * 8);
  load_lds16(n_src + (size_t)tid * 4,          sn_dst + (size_t)tid * 4);
  load_lds16(n_src + (size_t)(512 + tid) * 4,  sn_dst + (size_t)(512 + tid) * 4);
}

// A-stage: the recurrence (v4-proven DMA 2-ahead 3-buffer + counted vmcnt).
// Per-step vm ops: pf(4) + st(4 for L<=1 h-ring, 8 for L==2 out). End-of-step
// vmcnt(8)/(12) drains pf(t+1)+st(t-1). Publish mini-phase every 4 steps:
// all waves vmcnt(0) + barrier, tid0 rel_fence (data stages) + flag = t.
// Flag v => data <= v-1 visible AND own ring-reads <= v+1 complete.
template <int L>
DEVFN void gruA(char* smem,
                const unsigned short* rzsrc, const float* nsrc,
                const unsigned short* whh, const float* bhhn_l,
                const float* h0_l, float* outf, float* hTl,
                unsigned* hring_l, int* fBprod, int* fBself, int* fAself, int b) {
  auto h_bf = (unsigned short(*)[16][272])(smem);              // [2][16][272]
  auto srz  = (unsigned short(*)[8192])(smem + 17408);         // [3][8192]
  auto sn   = (float(*)[4096])(smem + 17408 + 49152);          // [3][4096]

  const int tid = threadIdx.x;
  const int w = tid >> 6, lane = tid & 63;
  const int q = lane >> 4, nl = lane & 15;
  const int cb = w * 32;

  // Whh fragments -> registers (launch_bounds(512,1) => 256-reg budget).
  short8_ wf[6][8];
#pragma unroll
  for (int c = 0; c < 2; ++c)
#pragma unroll
    for (int g = 0; g < 3; ++g) {
      const unsigned short* wrow = whh + (size_t)(g * 256 + cb + c * 16 + nl) * 256;
#pragma unroll
      for (int kt = 0; kt < 8; ++kt)
        wf[c * 3 + g][kt] = *(const short8_*)(wrow + kt * 32 + q * 8);
    }
  const float bn_[2] = { bhhn_l[cb + nl], bhhn_l[cb + 16 + nl] };

  float hold[2][4];
#pragma unroll
  for (int r = 0; r < 4; ++r) {
    hold[0][r] = h0_l[(b * 16 + q * 4 + r) * 256 + cb + nl];
    hold[1][r] = h0_l[(b * 16 + q * 4 + r) * 256 + cb + 16 + nl];
  }
#pragma unroll
  for (int r = 0; r < 4; ++r)
    *(unsigned*)&h_bf[0][q * 4 + r][cb + nl * 2] = cvt_pk_bf16(hold[0][r], hold[1][r]);

  int seenB = 0, seenBs = 0;
  if (L > 0) { seenB = pollGE(fBprod, 2); acq_fence(); }   // gx(0),gx(1) visible
  {
    const size_t b0 = (size_t)b * 1024;
    const size_t b1 = ((size_t)4 + b) * 1024;
    pfA(rzsrc + b0 * 8, nsrc + b0 * 4, &srz[0][0], &sn[0][0], tid);
    pfA(rzsrc + b1 * 8, nsrc + b1 * 4, &srz[1][0], &sn[1][0], tid);
  }
  asm volatile("s_waitcnt vmcnt(4) lgkmcnt(0)" ::: "memory");  // pf(0) done
  __builtin_amdgcn_s_barrier();
  asm volatile("" ::: "memory");

  int b3r = 0;  // LDS buffer holding gx(t)
  for (int t = 0; t < T_; ++t) {
    // ---- publish mini-phase (every 4 steps)
    if (((t & 3) == 0) && t >= 4) {
      asm volatile("s_waitcnt vmcnt(0) lgkmcnt(0)" ::: "memory");
      __builtin_amdgcn_s_barrier();
      if (tid == 0) {
        if (L <= 1) rel_fence();     // h-ring data release (wbl2)
        flag_pub(fAself, t);         // L==2: reuse-only flag, no fence
      }
    }
    const int tt = (t + 2 <= T_ - 1) ? t + 2 : T_ - 1;
    if (L > 0) {
      if (seenB < tt + 1) { seenB = pollGE(fBprod, tt + 1); acq_fence(); }
    }
    if (L <= 1) {
      if (t >= 16 && seenBs < t - 15) seenBs = pollGE(fBself, t - 15);  // reuse
    }
    {  // prefetch gx(t+2) -> LDS buffer (t+2)%3
      int b3w = b3r + 2; if (b3w >= 3) b3w -= 3;
      const size_t base = (L == 0 ? ((size_t)tt * 4 + b) : ((size_t)(tt & 15) * 4 + b)) * 1024;
      pfA(rzsrc + base * 8, nsrc + base * 4, &srz[b3w][0], &sn[b3w][0], tid);
    }
    asm volatile("" ::: "memory");   // pin pf-before-stores (vmcnt accounting)

    // ---- MFMA: gh = h . Whh^T from h_bf[t&1]
    float4_ acc[6];
    float4_ z4 = {0.f, 0.f, 0.f, 0.f};
#pragma unroll
    for (int u = 0; u < 6; ++u) acc[u] = z4;
    __builtin_amdgcn_s_setprio(1);
#pragma unroll
    for (int kt = 0; kt < 8; ++kt) {
      const short8_ af = *(const short8_*)&h_bf[t & 1][nl][kt * 32 + q * 8];
#pragma unroll
      for (int u = 0; u < 6; ++u)
        acc[u] = __builtin_amdgcn_mfma_f32_16x16x32_bf16(af, wf[u][kt], acc[u], 0, 0, 0);
    }
    __builtin_amdgcn_s_setprio(0);

    // ---- gates (lane-linear b128 fragment reads, conflict-free)
    const short8_ rzA = *(const short8_*)&srz[b3r][(size_t)tid * 8];
    const short8_ rzB = *(const short8_*)&srz[b3r][(size_t)(512 + tid) * 8];
    const float4_ xnA = *(const float4_*)&sn[b3r][(size_t)tid * 4];
    const float4_ xnB = *(const float4_*)&sn[b3r][(size_t)(512 + tid) * 4];
#pragma unroll
    for (int r = 0; r < 4; ++r) {
      float rr0 = sigmoid_(bf2f((unsigned short)rzA[r]) + acc[0][r]);
      float zz0 = sigmoid_(bf2f((unsigned short)rzA[4 + r]) + acc[1][r]);
      float nn0 = tanh_(xnA[r] + rr0 * (acc[2][r] + bn_[0]));
      float hv0 = nn0 + zz0 * (hold[0][r] - nn0);
      float rr1 = sigmoid_(bf2f((unsigned short)rzB[r]) + acc[3][r]);
      float zz1 = sigmoid_(bf2f((unsigned short)rzB[4 + r]) + acc[4][r]);
      float nn1 = tanh_(xnB[r] + rr1 * (acc[5][r] + bn_[1]));
      float hv1 = nn1 + zz1 * (hold[1][r] - nn1);
      hold[0][r] = hv0;
      hold[1][r] = hv1;
      const unsigned pk = cvt_pk_bf16(hv0, hv1);
      *(unsigned*)&h_bf[(t + 1) & 1][q * 4 + r][cb + nl * 2] = pk;
      if (L <= 1)
        hring_l[((size_t)(t & 15) * 4 + b) * 2048 + (size_t)(q * 4 + r) * 128 + (cb >> 1) + nl] = pk;
    }
    if (L == 2) {
      const size_t ob = ((size_t)t * 64 + b * 16) * 256;
#pragma unroll
      for (int r = 0; r < 4; ++r) {
        outf[ob + (size_t)(q * 4 + r) * 256 + cb + nl] = hold[0][r];
        outf[ob + (size_t)(q * 4 + r) * 256 + cb + 16 + nl] = hold[1][r];
      }
    }

    // ---- counted barrier: pf(t+1)+st(t-1) drained; pf(t+2)+st(t) in flight.
    asm volatile("" ::: "memory");
    if (L == 2) asm volatile("s_waitcnt vmcnt(12) lgkmcnt(0)" ::: "memory");
    else        asm volatile("s_waitcnt vmcnt(8) lgkmcnt(0)" ::: "memory");
    __builtin_amdgcn_sched_barrier(0);
    __builtin_amdgcn_s_barrier();
    asm volatile("" ::: "memory");
    b3r = (b3r == 2) ? 0 : b3r + 1;
  }

  // epilogue: final hidden state, then terminal flag
#pragma unroll
  for (int r = 0; r < 4; ++r) {
    hTl[(b * 16 + q * 4 + r) * 256 + cb + nl] = hold[0][r];
    hTl[(b * 16 + q * 4 + r) * 256 + cb + 16 + nl] = hold[1][r];
  }
  asm volatile("s_waitcnt vmcnt(0) lgkmcnt(0)" ::: "memory");
  __builtin_amdgcn_s_barrier();
  if (tid == 0 && fAself) {
    if (L <= 1) rel_fence();
    flag_pub(fAself, T_ + 2);
  }
}

// B-stage: gx_{L+1}(t) = h_L(t) @ Wih^T + bias -> fragment ring.
// No per-step barrier (no LDS; waves independent). h loads plain, in-step,
// 2-group (v4-proven, fits 256 VGPR). Stores drained at publish mini-phase.
DEVFN void gruB(const unsigned* hring_l, const unsigned short* wih, const float* bias,
                unsigned short* rzdst, float* ndst,
                int* fAh, int* fAnext, int* fBself, int b) {
  const int tid = threadIdx.x;
  const int w = tid >> 6, lane = tid & 63;
  const int q = lane >> 4, nl = lane & 15;
  const int cb = w * 32;

  short8_ wf[6][8];
#pragma unroll
  for (int c = 0; c < 2; ++c)
#pragma unroll
    for (int g = 0; g < 3; ++g) {
      const unsigned short* wrow = wih + (size_t)(g * 256 + cb + c * 16 + nl) * 256;
#pragma unroll
      for (int kt = 0; kt < 8; ++kt)
        wf[c * 3 + g][kt] = *(const short8_*)(wrow + kt * 32 + q * 8);
    }
  float bv[6];
#pragma unroll
  for (int c = 0; c < 2; ++c)
#pragma unroll
    for (int g = 0; g < 3; ++g) bv[c * 3 + g] = bias[g * 256 + cb + c * 16 + nl];

  int seenA = 0, seenAn = 0;
  for (int t = 0; t < T_; ++t) {
    // ---- publish mini-phase (every 4 steps)
    if (((t & 3) == 0) && t >= 4) {
      asm volatile("s_waitcnt vmcnt(0) lgkmcnt(0)" ::: "memory");
      __builtin_amdgcn_s_barrier();
      if (tid == 0) { rel_fence(); flag_pub(fBself, t); }
    }
    if (seenA < t + 1) { seenA = pollGE(fAh, t + 1); acq_fence(); }   // h(t) visible
    if (t >= 16 && seenAn < t - 15) seenAn = pollGE(fAnext, t - 15);  // gx reuse

    const unsigned* hrow = hring_l + ((size_t)(t & 15) * 4 + b) * 2048 + (size_t)nl * 128;
    float4_ acc[6];
    float4_ z4 = {0.f, 0.f, 0.f, 0.f};
#pragma unroll
    for (int u = 0; u < 6; ++u) acc[u] = z4;
#pragma unroll
    for (int h = 0; h < 2; ++h) {
      short8_ af4[4];
#pragma unroll
      for (int k = 0; k < 4; ++k)
        af4[k] = *(const short8_*)(hrow + (h * 4 + k) * 16 + q * 4);
      __builtin_amdgcn_s_setprio(1);
#pragma unroll
      for (int k = 0; k < 4; ++k)
#pragma unroll
        for (int u = 0; u < 6; ++u)
          acc[u] = __builtin_amdgcn_mfma_f32_16x16x32_bf16(af4[k], wf[u][h * 4 + k], acc[u], 0, 0, 0);
      __builtin_amdgcn_s_setprio(0);
    }

    const size_t base = ((size_t)(t & 15) * 4 + b) * 1024;
#pragma unroll
    for (int c = 0; c < 2; ++c) {
      const int ch = c * 512 + w * 64 + q * 16 + nl;
      uint4_ rv;
      rv[0] = cvt_pk_bf16(acc[c * 3 + 0][0] + bv[c * 3 + 0], acc[c * 3 + 0][1] + bv[c * 3 + 0]);
      rv[1] = cvt_pk_bf16(acc[c * 3 + 0][2] + bv[c * 3 + 0], acc[c * 3 + 0][3] + bv[c * 3 + 0]);
      rv[2] = cvt_pk_bf16(acc[c * 3 + 1][0] + bv[c * 3 + 1], acc[c * 3 + 1][1] + bv[c * 3 + 1]);
      rv[3] = cvt_pk_bf16(acc[c * 3 + 1][2] + bv[c * 3 + 1], acc[c * 3 + 1][3] + bv[c * 3 + 1]);
      *(uint4_*)(rzdst + (base + ch) * 8) = rv;
      float4_ nv;
#pragma unroll
      for (int r = 0; r < 4; ++r) nv[r] = acc[c * 3 + 2][r] + bv[c * 3 + 2];
      *(float4_*)(ndst + (base + ch) * 4) = nv;
    }
  }

  asm volatile("s_waitcnt vmcnt(0) lgkmcnt(0)" ::: "memory");
  __builtin_amdgcn_s_barrier();
  if (tid == 0) { rel_fence(); flag_pub(fBself, T_ + 2); }
}

// -------------------------------------------------------------- pipeline -----
__global__ __launch_bounds__(512, 1) void gru_pipeline(
    const unsigned short* __restrict__ gxrz0, const float* __restrict__ gxn0,
    unsigned short* __restrict__ rzring, float* __restrict__ nring,
    unsigned* __restrict__ hring,
    const unsigned short* __restrict__ whhb, const unsigned short* __restrict__ wihb,
    const float* __restrict__ biasf, const float* __restrict__ bhhn,
    const float* __restrict__ h0, float* __restrict__ out, float* __restrict__ hT,
    int* __restrict__ flags) {
  __shared__ alignas(16) char smem[17408 + 49152 + 49152];
  const int bid = (int)blockIdx.x;
  const int role = bid >> 3, b = bid & 7;
  if (b >= 4) return;   // XCD-chain placement heuristic: chain b on XCD b
  int* fA = flags;        // [3][4]: A-stage progress flags
  int* fB = flags + 12;   // [2][4]: B-stage progress flags

  if (role == 0) {
    gruA<0>(smem, gxrz0, gxn0, whhb, bhhn, h0, nullptr, hT,
            hring, nullptr, &fB[b], &fA[b], b);
  } else if (role == 1) {
    gruB(hring, wihb + (size_t)1 * G_ * H_, biasf + G_,
         rzring, nring, &fA[b], &fA[4 + b], &fB[b], b);
  } else if (role == 2) {
    gruA<1>(smem, rzring, nring, whhb + (size_t)1 * G_ * H_, bhhn + H_,
            h0 + B_ * H_, nullptr, hT + B_ * H_,
            hring + HRING_L, &fB[b], &fB[4 + b], &fA[4 + b], b);
  } else if (role == 3) {
    gruB(hring + HRING_L, wihb + (size_t)2 * G_ * H_, biasf + 2 * G_,
         rzring + RZRING_L, nring + NRING_L, &fA[4 + b], &fA[8 + b], &fB[4 + b], b);
  } else {
    gruA<2>(smem, rzring + RZRING_L, nring + NRING_L, whhb + (size_t)2 * G_ * H_,
            bhhn + 2 * H_, h0 + 2 * B_ * H_, out, hT + 2 * B_ * H_,
            nullptr, &fB[4 + b], nullptr, &fA[8 + b], b);
  }
}

// ------------------------------------------------------------------ launch ---
extern "C" void kernel_launch(void* const* d_in, const int* in_sizes, int n_in,
                              void* d_out, int out_size, void* d_ws, size_t ws_size,
                              hipStream_t stream) {
  (void)in_sizes; (void)n_in; (void)out_size; (void)ws_size;
  const float* x   = (const float*)d_in[0];
  const float* h0  = (const float*)d_in[1];
  const float* wih = (const float*)d_in[2];
  const float* whh = (const float*)d_in[3];
  const float* bih = (const float*)d_in[4];
  const float* bhh = (const float*)d_in[5];
  float* out = (float*)d_out;
  char* ws = (char*)d_ws;

  // workspace layout (within previous 405 MiB footprint)
  unsigned short* gxrz0 = (unsigned short*)(ws + 0);           // 134,217,728
  float*          gxn0  = (float*)(ws + 134217728);            // 134,217,728
  unsigned short* buf0  = (unsigned short*)(ws + 268435456);   //  67,108,864 (x bf16)
  unsigned*       hring = (unsigned*)(ws + 335544320);         //   1,048,576
  unsigned short* rzring= (unsigned short*)(ws + 336592896);   //   2,097,152
  float*          nring = (float*)(ws + 338690048);            //   2,097,152
  int*            flags = (int*)(ws + 340787200);              //         128
  unsigned short* wihb  = (unsigned short*)(ws + 402653184);   //   1,179,648
  unsigned short* whhb  = (unsigned short*)(ws + 403832832);   //   1,179,648
  float*         biasf  = (float*)(ws + 405012480);            //       9,216
  float*          bhhn  = (float*)(ws + 405021696);            //       3,072

  convert_kernel<<<2048, 256, 0, stream>>>(x, wih, whh, bih, bhh,
                                           buf0, wihb, whhb, biasf, bhhn, flags);
  gemm_gx<<<dim3(6, 1024), 256, 0, stream>>>(buf0, wihb, biasf, gxrz0, gxn0);
  gru_pipeline<<<40, 512, 0, stream>>>(gxrz0, gxn0, rzring, nring, hring,
                                       whhb, wihb, biasf, bhhn, h0,
                                       out, out + (size_t)T_ * B_ * H_, flags);
}